// Round 8
// baseline (211.172 us; speedup 1.0000x reference)
//
#include <hip/hip_runtime.h>
#include <hip/hip_bf16.h>

#define B_  2
#define S_  2048
#define H_  1024
#define NH_ 16
#define HD_ 64
#define NTOK (B_*S_)   // 4096

typedef __attribute__((ext_vector_type(8))) short bf16x8;
typedef __attribute__((ext_vector_type(4))) float f32x4;

#define SC2 0.18033688011112042f   // (1/sqrt(64)) * log2(e)

static __device__ __forceinline__ ushort f2bf(float f) {
    __hip_bfloat16 h = __float2bfloat16(f);
    return *reinterpret_cast<ushort*>(&h);
}
// single-instruction packed f32x2 -> bf16x2 (RNE), T12 recipe
static __device__ __forceinline__ uint cvt_pk_bf16(float lo, float hi) {
    uint r;
    asm("v_cvt_pk_bf16_f32 %0, %1, %2" : "=v"(r) : "v"(lo), "v"(hi));
    return r;
}

static __device__ __forceinline__ void gload_lds16(const void* g, void* l) {
    __builtin_amdgcn_global_load_lds(
        (const __attribute__((address_space(1))) void*)g,
        (__attribute__((address_space(3))) void*)l,
        16, 0, 0);
}

// ---------------------------------------------------------------
// f32 -> bf16 bulk converts
// ---------------------------------------------------------------
__global__ __launch_bounds__(256) void f32_to_bf16(
    const float* __restrict__ s, ushort* __restrict__ d, int n8)
{
    const int i = blockIdx.x * 256 + threadIdx.x;
    if (i >= n8) return;
    const float4 a = reinterpret_cast<const float4*>(s)[2*i + 0];
    const float4 b = reinterpret_cast<const float4*>(s)[2*i + 1];
    ushort u[8];
    u[0] = f2bf(a.x); u[1] = f2bf(a.y); u[2] = f2bf(a.z); u[3] = f2bf(a.w);
    u[4] = f2bf(b.x); u[5] = f2bf(b.y); u[6] = f2bf(b.z); u[7] = f2bf(b.w);
    reinterpret_cast<uint4*>(d)[i] = *reinterpret_cast<uint4*>(u);
}

struct Cvt4 { const float* s[4]; ushort* d[4]; };
__global__ __launch_bounds__(256) void w_to_bf16(Cvt4 a, int n8)
{
    const int z = blockIdx.y;
    const int i = blockIdx.x * 256 + threadIdx.x;
    if (i >= n8) return;
    const float* s = a.s[z];
    const float4 va = reinterpret_cast<const float4*>(s)[2*i + 0];
    const float4 vb = reinterpret_cast<const float4*>(s)[2*i + 1];
    ushort u[8];
    u[0] = f2bf(va.x); u[1] = f2bf(va.y); u[2] = f2bf(va.z); u[3] = f2bf(va.w);
    u[4] = f2bf(vb.x); u[5] = f2bf(vb.y); u[6] = f2bf(vb.z); u[7] = f2bf(vb.w);
    reinterpret_cast<uint4*>(a.d[z])[i] = *reinterpret_cast<uint4*>(u);
}

// ---------------------------------------------------------------
// V [tok][H] bf16 -> Vt [(b*NH+h)][d][s] bf16
// ---------------------------------------------------------------
__global__ __launch_bounds__(256) void transpose_v(
    const ushort* __restrict__ Vb, ushort* __restrict__ Vt)
{
    __shared__ ushort T[64][72];
    const int t  = threadIdx.x;
    const int b  = blockIdx.z;
    const int h  = blockIdx.y;
    const int s0 = blockIdx.x * 64;
    const int r  = t >> 2;
    const int c0 = (t & 3) * 16;

    const ushort* src = Vb + (size_t)(b*S_ + s0 + r)*H_ + h*HD_ + c0;
    *reinterpret_cast<uint4*>(&T[r][c0])     = *reinterpret_cast<const uint4*>(src);
    *reinterpret_cast<uint4*>(&T[r][c0 + 8]) = *reinterpret_cast<const uint4*>(src + 8);
    __syncthreads();

    const int d = r;
    ushort tmp[16];
#pragma unroll
    for (int k = 0; k < 16; ++k) tmp[k] = T[c0 + k][d];
    ushort* dst = Vt + ((size_t)((b*NH_ + h)*HD_ + d))*S_ + s0 + c0;
    *reinterpret_cast<uint4*>(dst)     = *reinterpret_cast<uint4*>(&tmp[0]);
    *reinterpret_cast<uint4*>(dst + 8) = *reinterpret_cast<uint4*>(&tmp[8]);
}

// ---------------------------------------------------------------
// MFMA GEMM: Y = A(bf16,[M,K]) @ W(bf16,[N,K])^T + bias(f32)
// ---------------------------------------------------------------
struct GemmArgs {
    const ushort* W[3];
    const float*  bias[3];
    void*         Y[3];
};

template<int MREP, bool BF16OUT>
__global__ __launch_bounds__(256) void gemm_mfma_bt(
    const ushort* __restrict__ A, GemmArgs args, int M, int N, int K)
{
    constexpr int BM = MREP * 32;
    __shared__ __align__(16) ushort As[BM * 64];
    __shared__ __align__(16) ushort Bs[128 * 64];

    const int z = blockIdx.z;
    const ushort* __restrict__ W   = args.W[z];
    const float*  __restrict__ bia = args.bias[z];

    const int t  = threadIdx.x;
    const int w  = t >> 6;
    const int l  = t & 63;
    const int lq = l >> 4;
    const int ln = l & 15;
    const int wr = w >> 1;
    const int wc = w & 1;
    const int m0 = blockIdx.x * BM;
    const int n0 = blockIdx.y * 128;
    const int srow = l >> 3;
    const int scol = (l & 7) * 8;

    f32x4 acc[MREP][4];
#pragma unroll
    for (int m = 0; m < MREP; ++m)
#pragma unroll
        for (int n = 0; n < 4; ++n) acc[m][n] = f32x4{0.f, 0.f, 0.f, 0.f};

    for (int k0 = 0; k0 < K; k0 += 64) {
        __syncthreads();
#pragma unroll
        for (int i = 0; i < BM/32; ++i) {
            const int rb = i*32 + w*8;
            gload_lds16(A + (size_t)(m0 + rb + srow)*K + k0 + scol, &As[rb*64]);
        }
#pragma unroll
        for (int i = 0; i < 4; ++i) {
            const int rb = i*32 + w*8;
            gload_lds16(W + (size_t)(n0 + rb + srow)*K + k0 + scol, &Bs[rb*64]);
        }
        __syncthreads();
#pragma unroll
        for (int ks = 0; ks < 2; ++ks) {
            bf16x8 bfr[4];
#pragma unroll
            for (int n = 0; n < 4; ++n)
                bfr[n] = *reinterpret_cast<const bf16x8*>(&Bs[(wc*64 + n*16 + ln)*64 + ks*32 + lq*8]);
#pragma unroll
            for (int m = 0; m < MREP; ++m) {
                const bf16x8 afr = *reinterpret_cast<const bf16x8*>(&As[(wr*MREP*16 + m*16 + ln)*64 + ks*32 + lq*8]);
#pragma unroll
                for (int n = 0; n < 4; ++n)
                    acc[m][n] = __builtin_amdgcn_mfma_f32_16x16x32_bf16(afr, bfr[n], acc[m][n], 0, 0, 0);
            }
        }
    }

    float bv[4];
#pragma unroll
    for (int n = 0; n < 4; ++n) bv[n] = bia[n0 + wc*64 + n*16 + ln];

#pragma unroll
    for (int m = 0; m < MREP; ++m) {
#pragma unroll
        for (int r = 0; r < 4; ++r) {
            const size_t row = (size_t)(m0 + wr*MREP*16 + m*16 + lq*4 + r);
#pragma unroll
            for (int n = 0; n < 4; ++n) {
                const int col = n0 + wc*64 + n*16 + ln;
                const float val = acc[m][n][r] + bv[n];
                if constexpr (BF16OUT)
                    ((ushort*)args.Y[z])[row*N + col] = f2bf(val);
                else
                    ((float*)args.Y[z])[row*N + col] = val;
            }
        }
    }
}

// ---------------------------------------------------------------
// attn_pv (round 8): QB=64, swapped QK^T, deferred normalization.
// K AND V double-buffered, prefetch a FULL tile ahead, ONE barrier
// per tile. P pack via v_cvt_pk_bf16_f32; Ps XOR-swizzled [16][64];
// 4-way lsum accumulators. LDS = 40960 B -> 4 blocks/CU.
// ---------------------------------------------------------------
__global__ __launch_bounds__(256) void attn_pv(
    const ushort* __restrict__ Qb, const ushort* __restrict__ Kb,
    const ushort* __restrict__ Vtg, ushort* __restrict__ ctx,
    float* __restrict__ il2_g)
{
    __shared__ __align__(16) ushort Ks[2][64*64];   // swizzled K tiles (dbuf)
    __shared__ __align__(16) ushort Vs[2][64*64];   // swizzled V^T tiles (dbuf)
    __shared__ __align__(16) ushort Ps[4][16*64];   // per-wave P, XOR-swizzled

    const int t  = threadIdx.x;
    const int w  = t >> 6;
    const int l  = t & 63;
    const int lq = l >> 4;
    const int ln = l & 15;
    const int b  = blockIdx.z;
    const int h  = blockIdx.y;
    const int q0 = blockIdx.x * 64;
    const int ln7 = ln & 7;

    // Q B-fragments (registers): q = q0 + w*16 + ln
    bf16x8 qf[2];
    {
        const ushort* qrow = Qb + ((size_t)(b*S_ + q0 + w*16 + ln))*H_ + h*HD_ + lq*8;
        qf[0] = *reinterpret_cast<const bf16x8*>(qrow);
        qf[1] = *reinterpret_cast<const bf16x8*>(qrow + 32);
    }

    // staging: thread covers chunks {t, 256+t}; swizzled source (T21)
    size_t koff[2], voff[2];
    int    dsto[2];
#pragma unroll
    for (int i = 0; i < 2; ++i) {
        const int chunk = i*256 + t;
        const int row   = chunk >> 3;
        const int c8    = (chunk & 7) ^ (row & 7);
        koff[i] = (size_t)(b*S_ + row)*H_ + h*HD_ + c8*8;
        voff[i] = ((size_t)((b*NH_ + h)*HD_ + row))*S_ + c8*8;
        dsto[i] = chunk*8;
    }

    float ls[4] = {0.f, 0.f, 0.f, 0.f};
    f32x4 oacc[4];
#pragma unroll
    for (int nt = 0; nt < 4; ++nt) oacc[nt] = f32x4{0.f, 0.f, 0.f, 0.f};

    // prologue: stage K(0), V(0) into buf 0
#pragma unroll
    for (int i = 0; i < 2; ++i) {
        gload_lds16(Kb + koff[i], &Ks[0][dsto[i]]);
        gload_lds16(Vtg + voff[i], &Vs[0][dsto[i]]);
    }
    __syncthreads();

    int cur = 0;
    for (int kt = 0; kt < S_; kt += 64) {
        // prefetch next tile (K and V) a full tile ahead
        if (kt + 64 < S_) {
#pragma unroll
            for (int i = 0; i < 2; ++i) {
                gload_lds16(Kb + koff[i] + (size_t)(kt + 64)*H_, &Ks[cur ^ 1][dsto[i]]);
                gload_lds16(Vtg + voff[i] + (kt + 64), &Vs[cur ^ 1][dsto[i]]);
            }
        }

        // swapped QK^T from Ks[cur]
        const ushort* ksb = &Ks[cur][0];
        f32x4 sacc[4];
#pragma unroll
        for (int nt = 0; nt < 4; ++nt) sacc[nt] = f32x4{0.f, 0.f, 0.f, 0.f};
#pragma unroll
        for (int ks = 0; ks < 2; ++ks) {
            bf16x8 kb[4];
#pragma unroll
            for (int nt = 0; nt < 4; ++nt)
                kb[nt] = *reinterpret_cast<const bf16x8*>(
                    &ksb[(nt*16 + ln)*64 + (((ks*4 + lq) ^ ln7) * 8)]);
#pragma unroll
            for (int nt = 0; nt < 4; ++nt)
                sacc[nt] = __builtin_amdgcn_mfma_f32_16x16x32_bf16(
                    kb[nt], qf[ks], sacc[nt], 0, 0, 0);
        }

        // softmax numerators: e = exp2(s*SC2); 4-way lsum; cvt_pk pack;
        // Ps store XOR-swizzled (write chunk = (nt*2+(lq>>1))^ln7)
#pragma unroll
        for (int nt = 0; nt < 4; ++nt) {
            const float e0 = exp2f(sacc[nt][0] * SC2);
            const float e1 = exp2f(sacc[nt][1] * SC2);
            const float e2 = exp2f(sacc[nt][2] * SC2);
            const float e3 = exp2f(sacc[nt][3] * SC2);
            ls[nt] += (e0 + e1) + (e2 + e3);
            uint2 pk;
            pk.x = cvt_pk_bf16(e0, e1);
            pk.y = cvt_pk_bf16(e2, e3);
            const int wch = (nt*2 + (lq >> 1)) ^ ln7;
            *reinterpret_cast<uint2*>(&Ps[w][ln*64 + wch*8 + (lq & 1)*4]) = pk;
        }

        // PV from Vs[cur] + Ps (wave-private, in-order DS within wave)
        const ushort* vsb = &Vs[cur][0];
#pragma unroll
        for (int ks = 0; ks < 2; ++ks) {
            const bf16x8 pa = *reinterpret_cast<const bf16x8*>(
                &Ps[w][ln*64 + (((ks*4 + lq) ^ ln7) * 8)]);
#pragma unroll
            for (int nt = 0; nt < 4; ++nt) {
                const bf16x8 vb8 = *reinterpret_cast<const bf16x8*>(
                    &vsb[(nt*16 + ln)*64 + (((ks*4 + lq) ^ ln7) * 8)]);
                oacc[nt] = __builtin_amdgcn_mfma_f32_16x16x32_bf16(
                    pa, vb8, oacc[nt], 0, 0, 0);
            }
        }

        __syncthreads();   // own vmcnt drained -> next bufs landed; all waves done with cur
        cur ^= 1;
    }

    // row sum: combine 4 accumulators, reduce across lq groups (q = ln)
    float lsum = (ls[0] + ls[1]) + (ls[2] + ls[3]);
    lsum += __shfl_xor(lsum, 16);
    lsum += __shfl_xor(lsum, 32);
    const float invl = 1.f / lsum;

    if (lq == 0)
        il2_g[(size_t)(b*NH_ + h)*S_ + q0 + w*16 + ln] = -__log2f(lsum);

    // ctx write: oacc rows = q local lq*4+r -> invl of that row via shfl
    float ivr[4];
#pragma unroll
    for (int r = 0; r < 4; ++r) ivr[r] = __shfl(invl, lq*4 + r);
    ushort* crow = ctx + ((size_t)(b*S_ + q0 + w*16 + lq*4))*H_ + h*HD_ + ln;
#pragma unroll
    for (int r = 0; r < 4; ++r)
#pragma unroll
        for (int nt = 0; nt < 4; ++nt)
            crow[(size_t)r*H_ + nt*16] = f2bf(oacc[nt][r] * ivr[r]);
}

// ---------------------------------------------------------------
// attn_colsum (round 8): 64-key blocks, Q double-buffered prefetch,
// exponent-folded normalization, 4-way cs accumulators.
// LDS = 32768 B -> 5 blocks/CU.
// ---------------------------------------------------------------
__global__ __launch_bounds__(256) void attn_colsum(
    const ushort* __restrict__ Qb, const ushort* __restrict__ Kb,
    const float* __restrict__ il2_g, float* __restrict__ colsum)
{
    __shared__ __align__(16) ushort KsT[64*64];    // swizzled K tile
    __shared__ __align__(16) ushort Qs[2][64*64];  // swizzled Q tiles (dbuf)
    __shared__ __align__(16) float  iv[S_];        // il2 row for (b,h)

    const int t  = threadIdx.x;
    const int w  = t >> 6;
    const int l  = t & 63;
    const int lq = l >> 4;
    const int ln = l & 15;
    const int b  = blockIdx.z;
    const int h  = blockIdx.y;
    const int k0 = blockIdx.x * 64;
    const int bh = b*NH_ + h;
    const int ln7 = ln & 7;

    // staging chunk math
    int crow_[2], cc8[2], dsto[2];
#pragma unroll
    for (int i = 0; i < 2; ++i) {
        const int chunk = i*256 + t;
        crow_[i] = chunk >> 3;
        cc8[i]   = (chunk & 7) ^ (crow_[i] & 7);
        dsto[i]  = chunk*8;
    }

    // prologue: K tile + il2 row + Q(0)
#pragma unroll
    for (int i = 0; i < 2; ++i) {
        gload_lds16(Kb + (size_t)(b*S_ + k0 + crow_[i])*H_ + h*HD_ + cc8[i]*8, &KsT[dsto[i]]);
        gload_lds16(il2_g + (size_t)bh*S_ + (i*256 + t)*4, &iv[(i*256 + t)*4]);
        gload_lds16(Qb + (size_t)(b*S_ + crow_[i])*H_ + h*HD_ + cc8[i]*8, &Qs[0][dsto[i]]);
    }
    __syncthreads();

    // hoist this wave's K B-fragments (keys w*16 + ln)
    bf16x8 kf[2];
#pragma unroll
    for (int ks = 0; ks < 2; ++ks)
        kf[ks] = *reinterpret_cast<const bf16x8*>(
            &KsT[(w*16 + ln)*64 + (((ks*4 + lq) ^ ln7) * 8)]);

    float cs4[4] = {0.f, 0.f, 0.f, 0.f};

    int cur = 0;
    for (int qt = 0; qt < S_; qt += 64) {
        if (qt + 64 < S_) {
#pragma unroll
            for (int i = 0; i < 2; ++i)
                gload_lds16(Qb + (size_t)(b*S_ + qt + 64 + crow_[i])*H_ + h*HD_ + cc8[i]*8,
                            &Qs[cur ^ 1][dsto[i]]);
        }
        const ushort* qsb = &Qs[cur][0];

#pragma unroll
        for (int c = 0; c < 4; ++c) {
            f32x4 sacc = f32x4{0.f, 0.f, 0.f, 0.f};
#pragma unroll
            for (int ks = 0; ks < 2; ++ks) {
                const bf16x8 af = *reinterpret_cast<const bf16x8*>(
                    &qsb[(c*16 + ln)*64 + (((ks*4 + lq) ^ ln7) * 8)]);
                sacc = __builtin_amdgcn_mfma_f32_16x16x32_bf16(af, kf[ks], sacc, 0, 0, 0);
            }
            const f32x4 iv4 = *reinterpret_cast<const f32x4*>(&iv[qt + c*16 + lq*4]);
#pragma unroll
            for (int r = 0; r < 4; ++r)
                cs4[r] += exp2f(fmaf(sacc[r], SC2, iv4[r]));
        }

        __syncthreads();   // Q(t+1) landed; all waves done with Qs[cur]
        cur ^= 1;
    }

    float cs = (cs4[0] + cs4[1]) + (cs4[2] + cs4[3]);
    cs += __shfl_xor(cs, 16);
    cs += __shfl_xor(cs, 32);
    if (l < 16)
        atomicAdd(&colsum[(size_t)b*S_ + k0 + w*16 + l], cs);
}

__global__ void zero_f32(float* p, int n)
{
    const int i = blockIdx.x * 256 + threadIdx.x;
    if (i < n) p[i] = 0.f;
}

__global__ void avg_write(const float* __restrict__ colsum, float* __restrict__ out, float inv)
{
    const int i = blockIdx.x * 256 + threadIdx.x;
    if (i < NTOK) out[i] = colsum[i] * inv;
}

extern "C" void kernel_launch(void* const* d_in, const int* in_sizes, int n_in,
                              void* d_out, int out_size, void* d_ws, size_t ws_size,
                              hipStream_t stream)
{
    const float* x  = (const float*)d_in[0];
    const float* Wq = (const float*)d_in[1];
    const float* bq = (const float*)d_in[2];
    const float* Wk = (const float*)d_in[3];
    const float* bk = (const float*)d_in[4];
    const float* Wv = (const float*)d_in[5];
    const float* bv = (const float*)d_in[6];
    const float* Wo = (const float*)d_in[7];
    const float* bo = (const float*)d_in[8];

    float* out     = (float*)d_out;
    float* avg_out = out + (size_t)NTOK * H_;

    char* ws = (char*)d_ws;
    const size_t mat  = (size_t)NTOK * H_ * sizeof(ushort);   // 8 MB
    const size_t wmat = (size_t)H_ * H_ * sizeof(ushort);     // 2 MB
    ushort* xb   = (ushort*)(ws);                  // also ctx (x dead after projections)
    ushort* Qb   = (ushort*)(ws + mat);
    ushort* Kb   = (ushort*)(ws + 2*mat);
    ushort* Vb   = (ushort*)(ws + 3*mat);
    ushort* Vtg  = (ushort*)(ws + 4*mat);          // V^T [(b,h)][d][s]
    ushort* Wqb  = (ushort*)(ws + 5*mat);
    ushort* Wkb  = (ushort*)(ws + 5*mat + wmat);
    ushort* Wvb  = (ushort*)(ws + 5*mat + 2*wmat);
    ushort* Wob  = (ushort*)(ws + 5*mat + 3*wmat);
    float*  colsum = (float*)(ws + 5*mat + 4*wmat);                   // 16 KB
    float*  il2    = (float*)(ws + 5*mat + 4*wmat + 64*1024);         // 256 KB
    ushort* ctxb = xb;

    const dim3 blk(256);

    f32_to_bf16<<<dim3((NTOK*H_/8 + 255)/256), blk, 0, stream>>>(x, xb, NTOK*H_/8);
    {
        Cvt4 c;
        c.s[0] = Wq; c.s[1] = Wk; c.s[2] = Wv; c.s[3] = Wo;
        c.d[0] = Wqb; c.d[1] = Wkb; c.d[2] = Wvb; c.d[3] = Wob;
        w_to_bf16<<<dim3((H_*H_/8 + 255)/256, 4), blk, 0, stream>>>(c, H_*H_/8);
    }

    zero_f32<<<dim3((NTOK + 255)/256), blk, 0, stream>>>(colsum, NTOK);

    // fused QKV projections
    {
        GemmArgs ga;
        ga.W[0] = Wqb; ga.W[1] = Wkb; ga.W[2] = Wvb;
        ga.bias[0] = bq; ga.bias[1] = bk; ga.bias[2] = bv;
        ga.Y[0] = Qb; ga.Y[1] = Kb; ga.Y[2] = Vb;
        gemm_mfma_bt<4, true><<<dim3(NTOK/128, H_/128, 3), blk, 0, stream>>>(
            xb, ga, NTOK, H_, H_);
    }

    transpose_v<<<dim3(S_/64, NH_, B_), blk, 0, stream>>>(Vb, Vtg);

    attn_pv<<<dim3(S_/64, NH_, B_), blk, 0, stream>>>(Qb, Kb, Vtg, ctxb, il2);
    attn_colsum<<<dim3(S_/64, NH_, B_), blk, 0, stream>>>(Qb, Kb, il2, colsum);

    // out projection
    {
        GemmArgs ga;
        ga.W[0] = Wob; ga.W[1] = Wob; ga.W[2] = Wob;
        ga.bias[0] = bo; ga.bias[1] = bo; ga.bias[2] = bo;
        ga.Y[0] = out; ga.Y[1] = out; ga.Y[2] = out;
        gemm_mfma_bt<2, false><<<dim3(NTOK/64, H_/128, 1), blk, 0, stream>>>(
            ctxb, ga, NTOK, H_, H_);
    }

    avg_write<<<dim3((NTOK + 255)/256), blk, 0, stream>>>(colsum, avg_out, 1.f/((float)NH_ * (float)S_));
}

// Round 9
// 202.999 us; speedup vs baseline: 1.0403x; 1.0403x over previous
//
#include <hip/hip_runtime.h>
#include <hip/hip_bf16.h>

#define B_  2
#define S_  2048
#define H_  1024
#define NH_ 16
#define HD_ 64
#define NTOK (B_*S_)   // 4096

typedef __attribute__((ext_vector_type(8))) short bf16x8;
typedef __attribute__((ext_vector_type(4))) float f32x4;

#define SC2 0.18033688011112042f   // (1/sqrt(64)) * log2(e)

static __device__ __forceinline__ ushort f2bf(float f) {
    __hip_bfloat16 h = __float2bfloat16(f);
    return *reinterpret_cast<ushort*>(&h);
}
// single-instruction packed f32x2 -> bf16x2 (RNE), T12 recipe
static __device__ __forceinline__ uint cvt_pk_bf16(float lo, float hi) {
    uint r;
    asm("v_cvt_pk_bf16_f32 %0, %1, %2" : "=v"(r) : "v"(lo), "v"(hi));
    return r;
}

static __device__ __forceinline__ void gload_lds16(const void* g, void* l) {
    __builtin_amdgcn_global_load_lds(
        (const __attribute__((address_space(1))) void*)g,
        (__attribute__((address_space(3))) void*)l,
        16, 0, 0);
}

// ---------------------------------------------------------------
// f32 -> bf16 bulk converts
// ---------------------------------------------------------------
__global__ __launch_bounds__(256) void f32_to_bf16(
    const float* __restrict__ s, ushort* __restrict__ d, int n8)
{
    const int i = blockIdx.x * 256 + threadIdx.x;
    if (i >= n8) return;
    const float4 a = reinterpret_cast<const float4*>(s)[2*i + 0];
    const float4 b = reinterpret_cast<const float4*>(s)[2*i + 1];
    ushort u[8];
    u[0] = f2bf(a.x); u[1] = f2bf(a.y); u[2] = f2bf(a.z); u[3] = f2bf(a.w);
    u[4] = f2bf(b.x); u[5] = f2bf(b.y); u[6] = f2bf(b.z); u[7] = f2bf(b.w);
    reinterpret_cast<uint4*>(d)[i] = *reinterpret_cast<uint4*>(u);
}

struct Cvt4 { const float* s[4]; ushort* d[4]; };
__global__ __launch_bounds__(256) void w_to_bf16(Cvt4 a, int n8)
{
    const int z = blockIdx.y;
    const int i = blockIdx.x * 256 + threadIdx.x;
    if (i >= n8) return;
    const float* s = a.s[z];
    const float4 va = reinterpret_cast<const float4*>(s)[2*i + 0];
    const float4 vb = reinterpret_cast<const float4*>(s)[2*i + 1];
    ushort u[8];
    u[0] = f2bf(va.x); u[1] = f2bf(va.y); u[2] = f2bf(va.z); u[3] = f2bf(va.w);
    u[4] = f2bf(vb.x); u[5] = f2bf(vb.y); u[6] = f2bf(vb.z); u[7] = f2bf(vb.w);
    reinterpret_cast<uint4*>(a.d[z])[i] = *reinterpret_cast<uint4*>(u);
}

// ---------------------------------------------------------------
// V [tok][H] bf16 -> Vt [(b*NH+h)][d][s] bf16
// ---------------------------------------------------------------
__global__ __launch_bounds__(256) void transpose_v(
    const ushort* __restrict__ Vb, ushort* __restrict__ Vt)
{
    __shared__ ushort T[64][72];
    const int t  = threadIdx.x;
    const int b  = blockIdx.z;
    const int h  = blockIdx.y;
    const int s0 = blockIdx.x * 64;
    const int r  = t >> 2;
    const int c0 = (t & 3) * 16;

    const ushort* src = Vb + (size_t)(b*S_ + s0 + r)*H_ + h*HD_ + c0;
    *reinterpret_cast<uint4*>(&T[r][c0])     = *reinterpret_cast<const uint4*>(src);
    *reinterpret_cast<uint4*>(&T[r][c0 + 8]) = *reinterpret_cast<const uint4*>(src + 8);
    __syncthreads();

    const int d = r;
    ushort tmp[16];
#pragma unroll
    for (int k = 0; k < 16; ++k) tmp[k] = T[c0 + k][d];
    ushort* dst = Vt + ((size_t)((b*NH_ + h)*HD_ + d))*S_ + s0 + c0;
    *reinterpret_cast<uint4*>(dst)     = *reinterpret_cast<uint4*>(&tmp[0]);
    *reinterpret_cast<uint4*>(dst + 8) = *reinterpret_cast<uint4*>(&tmp[8]);
}

// ---------------------------------------------------------------
// MFMA GEMM: Y = (A(bf16,[M,K]) @ W(bf16,[N,K])^T + bias(f32)) * scale
// ---------------------------------------------------------------
struct GemmArgs {
    const ushort* W[3];
    const float*  bias[3];
    void*         Y[3];
    float         scale[3];
};

template<int MREP, bool BF16OUT>
__global__ __launch_bounds__(256) void gemm_mfma_bt(
    const ushort* __restrict__ A, GemmArgs args, int M, int N, int K)
{
    constexpr int BM = MREP * 32;
    __shared__ __align__(16) ushort As[BM * 64];
    __shared__ __align__(16) ushort Bs[128 * 64];

    const int z = blockIdx.z;
    const ushort* __restrict__ W   = args.W[z];
    const float*  __restrict__ bia = args.bias[z];
    const float sc = args.scale[z];

    const int t  = threadIdx.x;
    const int w  = t >> 6;
    const int l  = t & 63;
    const int lq = l >> 4;
    const int ln = l & 15;
    const int wr = w >> 1;
    const int wc = w & 1;
    const int m0 = blockIdx.x * BM;
    const int n0 = blockIdx.y * 128;
    const int srow = l >> 3;
    const int scol = (l & 7) * 8;

    f32x4 acc[MREP][4];
#pragma unroll
    for (int m = 0; m < MREP; ++m)
#pragma unroll
        for (int n = 0; n < 4; ++n) acc[m][n] = f32x4{0.f, 0.f, 0.f, 0.f};

    for (int k0 = 0; k0 < K; k0 += 64) {
        __syncthreads();
#pragma unroll
        for (int i = 0; i < BM/32; ++i) {
            const int rb = i*32 + w*8;
            gload_lds16(A + (size_t)(m0 + rb + srow)*K + k0 + scol, &As[rb*64]);
        }
#pragma unroll
        for (int i = 0; i < 4; ++i) {
            const int rb = i*32 + w*8;
            gload_lds16(W + (size_t)(n0 + rb + srow)*K + k0 + scol, &Bs[rb*64]);
        }
        __syncthreads();
#pragma unroll
        for (int ks = 0; ks < 2; ++ks) {
            bf16x8 bfr[4];
#pragma unroll
            for (int n = 0; n < 4; ++n)
                bfr[n] = *reinterpret_cast<const bf16x8*>(&Bs[(wc*64 + n*16 + ln)*64 + ks*32 + lq*8]);
#pragma unroll
            for (int m = 0; m < MREP; ++m) {
                const bf16x8 afr = *reinterpret_cast<const bf16x8*>(&As[(wr*MREP*16 + m*16 + ln)*64 + ks*32 + lq*8]);
#pragma unroll
                for (int n = 0; n < 4; ++n)
                    acc[m][n] = __builtin_amdgcn_mfma_f32_16x16x32_bf16(afr, bfr[n], acc[m][n], 0, 0, 0);
            }
        }
    }

    float bv[4];
#pragma unroll
    for (int n = 0; n < 4; ++n) bv[n] = bia[n0 + wc*64 + n*16 + ln];

#pragma unroll
    for (int m = 0; m < MREP; ++m) {
#pragma unroll
        for (int r = 0; r < 4; ++r) {
            const size_t row = (size_t)(m0 + wr*MREP*16 + m*16 + lq*4 + r);
#pragma unroll
            for (int n = 0; n < 4; ++n) {
                const int col = n0 + wc*64 + n*16 + ln;
                const float val = (acc[m][n][r] + bv[n]) * sc;
                if constexpr (BF16OUT)
                    ((ushort*)args.Y[z])[row*N + col] = f2bf(val);
                else
                    ((float*)args.Y[z])[row*N + col] = val;
            }
        }
    }
}

// ---------------------------------------------------------------
// attn_pv (round 9): QB=64, swapped QK^T on PRE-SCALED Q (no mul),
// lsum via MFMA-with-ones (no adds, no shuffles, layout matches oacc),
// deferred normalization, K/V double-buffered with named LDS arrays
// (compile-time ds offsets), one barrier per tile.
// ---------------------------------------------------------------
__global__ __launch_bounds__(256) void attn_pv(
    const ushort* __restrict__ Qb, const ushort* __restrict__ Kb,
    const ushort* __restrict__ Vtg, ushort* __restrict__ ctx,
    float* __restrict__ il2_g)
{
    __shared__ __align__(16) ushort Ks0[64*64];
    __shared__ __align__(16) ushort Ks1[64*64];
    __shared__ __align__(16) ushort Vs0[64*64];
    __shared__ __align__(16) ushort Vs1[64*64];
    __shared__ __align__(16) ushort Ps[4][16*64];   // per-wave P, XOR-swizzled

    const int t  = threadIdx.x;
    const int w  = t >> 6;
    const int l  = t & 63;
    const int lq = l >> 4;
    const int ln = l & 15;
    const int b  = blockIdx.z;
    const int h  = blockIdx.y;
    const int q0 = blockIdx.x * 64;
    const int ln7 = ln & 7;

    // Q B-fragments (registers): q = q0 + w*16 + ln  (Q pre-scaled by SC2)
    bf16x8 qf[2];
    {
        const ushort* qrow = Qb + ((size_t)(b*S_ + q0 + w*16 + ln))*H_ + h*HD_ + lq*8;
        qf[0] = *reinterpret_cast<const bf16x8*>(qrow);
        qf[1] = *reinterpret_cast<const bf16x8*>(qrow + 32);
    }

    // ones B-fragment for the lsum MFMA
    bf16x8 onesb;
#pragma unroll
    for (int j = 0; j < 8; ++j) onesb[j] = (short)0x3F80;

    // staging: thread covers chunks {t, 256+t}; swizzled source (T21)
    size_t koff[2], voff[2];
    int    dsto[2];
#pragma unroll
    for (int i = 0; i < 2; ++i) {
        const int chunk = i*256 + t;
        const int row   = chunk >> 3;
        const int c8    = (chunk & 7) ^ (row & 7);
        koff[i] = (size_t)(b*S_ + row)*H_ + h*HD_ + c8*8;
        voff[i] = ((size_t)((b*NH_ + h)*HD_ + row))*S_ + c8*8;
        dsto[i] = chunk*8;
    }

    f32x4 lsacc = f32x4{0.f, 0.f, 0.f, 0.f};
    f32x4 oacc[4];
#pragma unroll
    for (int nt = 0; nt < 4; ++nt) oacc[nt] = f32x4{0.f, 0.f, 0.f, 0.f};

    auto tile_body = [&](const ushort* __restrict__ ksb, const ushort* __restrict__ vsb,
                         int pre_kt, bool do_pre,
                         ushort* __restrict__ kdst, ushort* __restrict__ vdst) {
        // prefetch next tile (K and V)
        if (do_pre) {
#pragma unroll
            for (int i = 0; i < 2; ++i) {
                gload_lds16(Kb + koff[i] + (size_t)pre_kt*H_, &kdst[dsto[i]]);
                gload_lds16(Vtg + voff[i] + pre_kt, &vdst[dsto[i]]);
            }
        }

        // swapped QK^T (scores already in log2 units via pre-scaled Q)
        f32x4 sacc[4];
#pragma unroll
        for (int nt = 0; nt < 4; ++nt) sacc[nt] = f32x4{0.f, 0.f, 0.f, 0.f};
#pragma unroll
        for (int ks = 0; ks < 2; ++ks) {
            bf16x8 kb[4];
#pragma unroll
            for (int nt = 0; nt < 4; ++nt)
                kb[nt] = *reinterpret_cast<const bf16x8*>(
                    &ksb[(nt*16 + ln)*64 + (((ks*4 + lq) ^ ln7) * 8)]);
#pragma unroll
            for (int nt = 0; nt < 4; ++nt)
                sacc[nt] = __builtin_amdgcn_mfma_f32_16x16x32_bf16(
                    kb[nt], qf[ks], sacc[nt], 0, 0, 0);
        }

        // numerators: e = exp2(s); pack; XOR-swizzled Ps store (no mul, no add)
#pragma unroll
        for (int nt = 0; nt < 4; ++nt) {
            const float e0 = exp2f(sacc[nt][0]);
            const float e1 = exp2f(sacc[nt][1]);
            const float e2 = exp2f(sacc[nt][2]);
            const float e3 = exp2f(sacc[nt][3]);
            uint2 pk;
            pk.x = cvt_pk_bf16(e0, e1);
            pk.y = cvt_pk_bf16(e2, e3);
            const int wch = (nt*2 + (lq >> 1)) ^ ln7;
            *reinterpret_cast<uint2*>(&Ps[w][ln*64 + wch*8 + (lq & 1)*4]) = pk;
        }

        // PV + lsum (Ps wave-private, DS in-order within wave)
#pragma unroll
        for (int ks = 0; ks < 2; ++ks) {
            const bf16x8 pa = *reinterpret_cast<const bf16x8*>(
                &Ps[w][ln*64 + (((ks*4 + lq) ^ ln7) * 8)]);
            lsacc = __builtin_amdgcn_mfma_f32_16x16x32_bf16(pa, onesb, lsacc, 0, 0, 0);
#pragma unroll
            for (int nt = 0; nt < 4; ++nt) {
                const bf16x8 vb8 = *reinterpret_cast<const bf16x8*>(
                    &vsb[(nt*16 + ln)*64 + (((ks*4 + lq) ^ ln7) * 8)]);
                oacc[nt] = __builtin_amdgcn_mfma_f32_16x16x32_bf16(
                    pa, vb8, oacc[nt], 0, 0, 0);
            }
        }

        __syncthreads();   // drains own vmcnt -> prefetched bufs landed
    };

    // prologue: stage tile 0 into buf 0
#pragma unroll
    for (int i = 0; i < 2; ++i) {
        gload_lds16(Kb + koff[i], &Ks0[dsto[i]]);
        gload_lds16(Vtg + voff[i], &Vs0[dsto[i]]);
    }
    __syncthreads();

    for (int kt = 0; kt < S_; kt += 128) {
        tile_body(Ks0, Vs0, kt + 64, true, Ks1, Vs1);
        tile_body(Ks1, Vs1, kt + 128, kt + 128 < S_, Ks0, Vs0);
    }

    // lsacc[r] = lsum for q = q0 + w*16 + lq*4 + r (identical across ln)
    float ivr[4];
#pragma unroll
    for (int r = 0; r < 4; ++r) ivr[r] = 1.f / lsacc[r];

    if (ln == 0) {
        float4 o;
        o.x = -__log2f(lsacc[0]);
        o.y = -__log2f(lsacc[1]);
        o.z = -__log2f(lsacc[2]);
        o.w = -__log2f(lsacc[3]);
        *reinterpret_cast<float4*>(
            il2_g + (size_t)(b*NH_ + h)*S_ + q0 + w*16 + lq*4) = o;
    }

    // ctx write: oacc rows = q local lq*4+r; same layout as lsacc -> no shuffles
    ushort* crow = ctx + ((size_t)(b*S_ + q0 + w*16 + lq*4))*H_ + h*HD_ + ln;
#pragma unroll
    for (int r = 0; r < 4; ++r)
#pragma unroll
        for (int nt = 0; nt < 4; ++nt)
            crow[(size_t)r*H_ + nt*16] = f2bf(oacc[nt][r] * ivr[r]);
}

// ---------------------------------------------------------------
// attn_colsum (round 9): 64-key blocks, Q double-buffered with named
// LDS arrays (compile-time offsets), pre-scaled Q (add, no fma),
// exponent-folded normalization, 4-way cs accumulators.
// ---------------------------------------------------------------
__global__ __launch_bounds__(256) void attn_colsum(
    const ushort* __restrict__ Qb, const ushort* __restrict__ Kb,
    const float* __restrict__ il2_g, float* __restrict__ colsum)
{
    __shared__ __align__(16) ushort KsT[64*64];    // swizzled K tile
    __shared__ __align__(16) ushort Qs0[64*64];
    __shared__ __align__(16) ushort Qs1[64*64];
    __shared__ __align__(16) float  iv[S_];        // il2 row for (b,h)

    const int t  = threadIdx.x;
    const int w  = t >> 6;
    const int l  = t & 63;
    const int lq = l >> 4;
    const int ln = l & 15;
    const int b  = blockIdx.z;
    const int h  = blockIdx.y;
    const int k0 = blockIdx.x * 64;
    const int bh = b*NH_ + h;
    const int ln7 = ln & 7;

    // staging chunk math
    int crow_[2], cc8[2], dsto[2];
#pragma unroll
    for (int i = 0; i < 2; ++i) {
        const int chunk = i*256 + t;
        crow_[i] = chunk >> 3;
        cc8[i]   = (chunk & 7) ^ (crow_[i] & 7);
        dsto[i]  = chunk*8;
    }

    // prologue: K tile + il2 row + Q(0)
#pragma unroll
    for (int i = 0; i < 2; ++i) {
        gload_lds16(Kb + (size_t)(b*S_ + k0 + crow_[i])*H_ + h*HD_ + cc8[i]*8, &KsT[dsto[i]]);
        gload_lds16(il2_g + (size_t)bh*S_ + (i*256 + t)*4, &iv[(i*256 + t)*4]);
        gload_lds16(Qb + (size_t)(b*S_ + crow_[i])*H_ + h*HD_ + cc8[i]*8, &Qs0[dsto[i]]);
    }
    __syncthreads();

    // hoist this wave's K B-fragments (keys w*16 + ln)
    bf16x8 kf[2];
#pragma unroll
    for (int ks = 0; ks < 2; ++ks)
        kf[ks] = *reinterpret_cast<const bf16x8*>(
            &KsT[(w*16 + ln)*64 + (((ks*4 + lq) ^ ln7) * 8)]);

    float cs4[4] = {0.f, 0.f, 0.f, 0.f};

    auto tile_body = [&](const ushort* __restrict__ qsb,
                         int pre_qt, bool do_pre, ushort* __restrict__ qdst) {
        if (do_pre) {
#pragma unroll
            for (int i = 0; i < 2; ++i)
                gload_lds16(Qb + (size_t)(b*S_ + pre_qt + crow_[i])*H_ + h*HD_ + cc8[i]*8,
                            &qdst[dsto[i]]);
        }
#pragma unroll
        for (int c = 0; c < 4; ++c) {
            f32x4 sacc = f32x4{0.f, 0.f, 0.f, 0.f};
#pragma unroll
            for (int ks = 0; ks < 2; ++ks) {
                const bf16x8 af = *reinterpret_cast<const bf16x8*>(
                    &qsb[(c*16 + ln)*64 + (((ks*4 + lq) ^ ln7) * 8)]);
                sacc = __builtin_amdgcn_mfma_f32_16x16x32_bf16(af, kf[ks], sacc, 0, 0, 0);
            }
            const f32x4 iv4 = *reinterpret_cast<const f32x4*>(&iv[(c*16 + lq*4) + 0]);
            // NOTE: iv index depends on qt; pass qt via captured variable below
            (void)iv4;
        }
        __syncthreads();
    };
    (void)tile_body;  // replaced by explicit loop below (need qt for iv index)

    int qt = 0;
    for (; qt < S_; qt += 128) {
        // phase A: compute Qs0, prefetch qt+64 -> Qs1
#pragma unroll
        for (int i = 0; i < 2; ++i)
            gload_lds16(Qb + (size_t)(b*S_ + qt + 64 + crow_[i])*H_ + h*HD_ + cc8[i]*8,
                        &Qs1[dsto[i]]);
#pragma unroll
        for (int c = 0; c < 4; ++c) {
            f32x4 sacc = f32x4{0.f, 0.f, 0.f, 0.f};
#pragma unroll
            for (int ks = 0; ks < 2; ++ks) {
                const bf16x8 af = *reinterpret_cast<const bf16x8*>(
                    &Qs0[(c*16 + ln)*64 + (((ks*4 + lq) ^ ln7) * 8)]);
                sacc = __builtin_amdgcn_mfma_f32_16x16x32_bf16(af, kf[ks], sacc, 0, 0, 0);
            }
            const f32x4 iv4 = *reinterpret_cast<const f32x4*>(&iv[qt + c*16 + lq*4]);
#pragma unroll
            for (int r = 0; r < 4; ++r)
                cs4[r] += exp2f(sacc[r] + iv4[r]);
        }
        __syncthreads();

        // phase B: compute Qs1, prefetch qt+128 -> Qs0
        if (qt + 128 < S_) {
#pragma unroll
            for (int i = 0; i < 2; ++i)
                gload_lds16(Qb + (size_t)(b*S_ + qt + 128 + crow_[i])*H_ + h*HD_ + cc8[i]*8,
                            &Qs0[dsto[i]]);
        }
#pragma unroll
        for (int c = 0; c < 4; ++c) {
            f32x4 sacc = f32x4{0.f, 0.f, 0.f, 0.f};
#pragma unroll
            for (int ks = 0; ks < 2; ++ks) {
                const bf16x8 af = *reinterpret_cast<const bf16x8*>(
                    &Qs1[(c*16 + ln)*64 + (((ks*4 + lq) ^ ln7) * 8)]);
                sacc = __builtin_amdgcn_mfma_f32_16x16x32_bf16(af, kf[ks], sacc, 0, 0, 0);
            }
            const f32x4 iv4 = *reinterpret_cast<const f32x4*>(&iv[qt + 64 + c*16 + lq*4]);
#pragma unroll
            for (int r = 0; r < 4; ++r)
                cs4[r] += exp2f(sacc[r] + iv4[r]);
        }
        __syncthreads();
    }

    float cs = (cs4[0] + cs4[1]) + (cs4[2] + cs4[3]);
    cs += __shfl_xor(cs, 16);
    cs += __shfl_xor(cs, 32);
    if (l < 16)
        atomicAdd(&colsum[(size_t)b*S_ + k0 + w*16 + l], cs);
}

__global__ void zero_f32(float* p, int n)
{
    const int i = blockIdx.x * 256 + threadIdx.x;
    if (i < n) p[i] = 0.f;
}

__global__ void avg_write(const float* __restrict__ colsum, float* __restrict__ out, float inv)
{
    const int i = blockIdx.x * 256 + threadIdx.x;
    if (i < NTOK) out[i] = colsum[i] * inv;
}

extern "C" void kernel_launch(void* const* d_in, const int* in_sizes, int n_in,
                              void* d_out, int out_size, void* d_ws, size_t ws_size,
                              hipStream_t stream)
{
    const float* x  = (const float*)d_in[0];
    const float* Wq = (const float*)d_in[1];
    const float* bq = (const float*)d_in[2];
    const float* Wk = (const float*)d_in[3];
    const float* bk = (const float*)d_in[4];
    const float* Wv = (const float*)d_in[5];
    const float* bv = (const float*)d_in[6];
    const float* Wo = (const float*)d_in[7];
    const float* bo = (const float*)d_in[8];

    float* out     = (float*)d_out;
    float* avg_out = out + (size_t)NTOK * H_;

    char* ws = (char*)d_ws;
    const size_t mat  = (size_t)NTOK * H_ * sizeof(ushort);   // 8 MB
    const size_t wmat = (size_t)H_ * H_ * sizeof(ushort);     // 2 MB
    ushort* xb   = (ushort*)(ws);                  // also ctx (x dead after projections)
    ushort* Qb   = (ushort*)(ws + mat);
    ushort* Kb   = (ushort*)(ws + 2*mat);
    ushort* Vb   = (ushort*)(ws + 3*mat);
    ushort* Vtg  = (ushort*)(ws + 4*mat);          // V^T [(b,h)][d][s]
    ushort* Wqb  = (ushort*)(ws + 5*mat);
    ushort* Wkb  = (ushort*)(ws + 5*mat + wmat);
    ushort* Wvb  = (ushort*)(ws + 5*mat + 2*wmat);
    ushort* Wob  = (ushort*)(ws + 5*mat + 3*wmat);
    float*  colsum = (float*)(ws + 5*mat + 4*wmat);                   // 16 KB
    float*  il2    = (float*)(ws + 5*mat + 4*wmat + 64*1024);         // 256 KB
    ushort* ctxb = xb;

    const dim3 blk(256);

    f32_to_bf16<<<dim3((NTOK*H_/8 + 255)/256), blk, 0, stream>>>(x, xb, NTOK*H_/8);
    {
        Cvt4 c;
        c.s[0] = Wq; c.s[1] = Wk; c.s[2] = Wv; c.s[3] = Wo;
        c.d[0] = Wqb; c.d[1] = Wkb; c.d[2] = Wvb; c.d[3] = Wob;
        w_to_bf16<<<dim3((H_*H_/8 + 255)/256, 4), blk, 0, stream>>>(c, H_*H_/8);
    }

    zero_f32<<<dim3((NTOK + 255)/256), blk, 0, stream>>>(colsum, NTOK);

    // fused QKV projections (Q pre-scaled by SC2 = scale/log2 fold)
    {
        GemmArgs ga;
        ga.W[0] = Wqb; ga.W[1] = Wkb; ga.W[2] = Wvb;
        ga.bias[0] = bq; ga.bias[1] = bk; ga.bias[2] = bv;
        ga.Y[0] = Qb; ga.Y[1] = Kb; ga.Y[2] = Vb;
        ga.scale[0] = SC2; ga.scale[1] = 1.f; ga.scale[2] = 1.f;
        gemm_mfma_bt<4, true><<<dim3(NTOK/128, H_/128, 3), blk, 0, stream>>>(
            xb, ga, NTOK, H_, H_);
    }

    transpose_v<<<dim3(S_/64, NH_, B_), blk, 0, stream>>>(Vb, Vtg);

    attn_pv<<<dim3(S_/64, NH_, B_), blk, 0, stream>>>(Qb, Kb, Vtg, ctxb, il2);
    attn_colsum<<<dim3(S_/64, NH_, B_), blk, 0, stream>>>(Qb, Kb, il2, colsum);

    // out projection
    {
        GemmArgs ga;
        ga.W[0] = Wob; ga.W[1] = Wob; ga.W[2] = Wob;
        ga.bias[0] = bo; ga.bias[1] = bo; ga.bias[2] = bo;
        ga.Y[0] = out; ga.Y[1] = out; ga.Y[2] = out;
        ga.scale[0] = 1.f; ga.scale[1] = 1.f; ga.scale[2] = 1.f;
        gemm_mfma_bt<2, false><<<dim3(NTOK/64, H_/128, 1), blk, 0, stream>>>(
            ctxb, ga, NTOK, H_, H_);
    }

    avg_write<<<dim3((NTOK + 255)/256), blk, 0, stream>>>(colsum, avg_out, 1.f/((float)NH_ * (float)S_));
}

// Round 10
// 182.989 us; speedup vs baseline: 1.1540x; 1.1094x over previous
//
#include <hip/hip_runtime.h>
#include <hip/hip_bf16.h>

#define B_  2
#define S_  2048
#define H_  1024
#define NH_ 16
#define HD_ 64
#define NTOK (B_*S_)   // 4096

typedef __attribute__((ext_vector_type(8))) short bf16x8;
typedef __attribute__((ext_vector_type(4))) float f32x4;

#define SC2 0.18033688011112042f   // (1/sqrt(64)) * log2(e)

static __device__ __forceinline__ ushort f2bf(float f) {
    __hip_bfloat16 h = __float2bfloat16(f);
    return *reinterpret_cast<ushort*>(&h);
}
static __device__ __forceinline__ uint cvt_pk_bf16(float lo, float hi) {
    uint r;
    asm("v_cvt_pk_bf16_f32 %0, %1, %2" : "=v"(r) : "v"(lo), "v"(hi));
    return r;
}

static __device__ __forceinline__ void gload_lds16(const void* g, void* l) {
    __builtin_amdgcn_global_load_lds(
        (const __attribute__((address_space(1))) void*)g,
        (__attribute__((address_space(3))) void*)l,
        16, 0, 0);
}

// ---------------------------------------------------------------
// prep: all f32->bf16 converts + colsum zero in ONE launch.
// blocks [0,2048): x ; [2048,4096): W's (512 each) ; [4096,4112): zero
// ---------------------------------------------------------------
struct PrepArgs {
    const float* src[5];   // x, Wq, Wk, Wv, Wo
    ushort*      dst[5];
    float*       zero;     // colsum
};

static __device__ __forceinline__ void conv8(const float* __restrict__ s,
                                             ushort* __restrict__ d, int i)
{
    const float4 a = reinterpret_cast<const float4*>(s)[2*i + 0];
    const float4 b = reinterpret_cast<const float4*>(s)[2*i + 1];
    ushort u[8];
    u[0] = f2bf(a.x); u[1] = f2bf(a.y); u[2] = f2bf(a.z); u[3] = f2bf(a.w);
    u[4] = f2bf(b.x); u[5] = f2bf(b.y); u[6] = f2bf(b.z); u[7] = f2bf(b.w);
    reinterpret_cast<uint4*>(d)[i] = *reinterpret_cast<uint4*>(u);
}

__global__ __launch_bounds__(256) void prep(PrepArgs a)
{
    int bid = blockIdx.x;
    const int t = threadIdx.x;
    if (bid < 2048) {                      // x: 524288 chunks
        conv8(a.src[0], a.dst[0], bid*256 + t);
        return;
    }
    bid -= 2048;
    if (bid < 2048) {                      // weights: 131072 chunks each
        const int wi = 1 + (bid >> 9);
        const int i  = (bid & 511)*256 + t;
        conv8(a.src[wi], a.dst[wi], i);
        return;
    }
    bid -= 2048;                           // zero colsum (16 blocks)
    const int i = bid*256 + t;
    if (i < NTOK) a.zero[i] = 0.f;
}

// ---------------------------------------------------------------
// V [tok][H] bf16 -> Vt [(b*NH+h)][d][s] bf16
// ---------------------------------------------------------------
__global__ __launch_bounds__(256) void transpose_v(
    const ushort* __restrict__ Vb, ushort* __restrict__ Vt)
{
    __shared__ ushort T[64][72];
    const int t  = threadIdx.x;
    const int b  = blockIdx.z;
    const int h  = blockIdx.y;
    const int s0 = blockIdx.x * 64;
    const int r  = t >> 2;
    const int c0 = (t & 3) * 16;

    const ushort* src = Vb + (size_t)(b*S_ + s0 + r)*H_ + h*HD_ + c0;
    *reinterpret_cast<uint4*>(&T[r][c0])     = *reinterpret_cast<const uint4*>(src);
    *reinterpret_cast<uint4*>(&T[r][c0 + 8]) = *reinterpret_cast<const uint4*>(src + 8);
    __syncthreads();

    const int d = r;
    ushort tmp[16];
#pragma unroll
    for (int k = 0; k < 16; ++k) tmp[k] = T[c0 + k][d];
    ushort* dst = Vt + ((size_t)((b*NH_ + h)*HD_ + d))*S_ + s0 + c0;
    *reinterpret_cast<uint4*>(dst)     = *reinterpret_cast<uint4*>(&tmp[0]);
    *reinterpret_cast<uint4*>(dst + 8) = *reinterpret_cast<uint4*>(&tmp[8]);
}

// ---------------------------------------------------------------
// MFMA GEMM (QKV, fused over z): Y = (A @ W^T + bias) * scale, bf16 out
// ---------------------------------------------------------------
struct GemmArgs {
    const ushort* W[3];
    const float*  bias[3];
    void*         Y[3];
    float         scale[3];
};

__global__ __launch_bounds__(256) void gemm_qkv(
    const ushort* __restrict__ A, GemmArgs args, int M, int N, int K)
{
    constexpr int MREP = 4;
    constexpr int BM = MREP * 32;
    __shared__ __align__(16) ushort As[BM * 64];
    __shared__ __align__(16) ushort Bs[128 * 64];

    const int z = blockIdx.z;
    const ushort* __restrict__ W   = args.W[z];
    const float*  __restrict__ bia = args.bias[z];
    const float sc = args.scale[z];

    const int t  = threadIdx.x;
    const int w  = t >> 6;
    const int l  = t & 63;
    const int lq = l >> 4;
    const int ln = l & 15;
    const int wr = w >> 1;
    const int wc = w & 1;
    const int m0 = blockIdx.x * BM;
    const int n0 = blockIdx.y * 128;
    const int srow = l >> 3;
    const int scol = (l & 7) * 8;

    f32x4 acc[MREP][4];
#pragma unroll
    for (int m = 0; m < MREP; ++m)
#pragma unroll
        for (int n = 0; n < 4; ++n) acc[m][n] = f32x4{0.f, 0.f, 0.f, 0.f};

    for (int k0 = 0; k0 < K; k0 += 64) {
        __syncthreads();
#pragma unroll
        for (int i = 0; i < BM/32; ++i) {
            const int rb = i*32 + w*8;
            gload_lds16(A + (size_t)(m0 + rb + srow)*K + k0 + scol, &As[rb*64]);
        }
#pragma unroll
        for (int i = 0; i < 4; ++i) {
            const int rb = i*32 + w*8;
            gload_lds16(W + (size_t)(n0 + rb + srow)*K + k0 + scol, &Bs[rb*64]);
        }
        __syncthreads();
#pragma unroll
        for (int ks = 0; ks < 2; ++ks) {
            bf16x8 bfr[4];
#pragma unroll
            for (int n = 0; n < 4; ++n)
                bfr[n] = *reinterpret_cast<const bf16x8*>(&Bs[(wc*64 + n*16 + ln)*64 + ks*32 + lq*8]);
#pragma unroll
            for (int m = 0; m < MREP; ++m) {
                const bf16x8 afr = *reinterpret_cast<const bf16x8*>(&As[(wr*MREP*16 + m*16 + ln)*64 + ks*32 + lq*8]);
#pragma unroll
                for (int n = 0; n < 4; ++n)
                    acc[m][n] = __builtin_amdgcn_mfma_f32_16x16x32_bf16(afr, bfr[n], acc[m][n], 0, 0, 0);
            }
        }
    }

    float bv[4];
#pragma unroll
    for (int n = 0; n < 4; ++n) bv[n] = bia[n0 + wc*64 + n*16 + ln];

    ushort* Y = (ushort*)args.Y[z];
#pragma unroll
    for (int m = 0; m < MREP; ++m) {
#pragma unroll
        for (int r = 0; r < 4; ++r) {
            const size_t row = (size_t)(m0 + wr*MREP*16 + m*16 + lq*4 + r);
#pragma unroll
            for (int n = 0; n < 4; ++n) {
                const int col = n0 + wc*64 + n*16 + ln;
                Y[row*N + col] = f2bf((acc[m][n][r] + bv[n]) * sc);
            }
        }
    }
}

// ---------------------------------------------------------------
// attn_pv (unchanged from round 9)
// ---------------------------------------------------------------
__global__ __launch_bounds__(256) void attn_pv(
    const ushort* __restrict__ Qb, const ushort* __restrict__ Kb,
    const ushort* __restrict__ Vtg, ushort* __restrict__ ctx,
    float* __restrict__ il2_g)
{
    __shared__ __align__(16) ushort Ks0[64*64];
    __shared__ __align__(16) ushort Ks1[64*64];
    __shared__ __align__(16) ushort Vs0[64*64];
    __shared__ __align__(16) ushort Vs1[64*64];
    __shared__ __align__(16) ushort Ps[4][16*64];   // per-wave P, XOR-swizzled

    const int t  = threadIdx.x;
    const int w  = t >> 6;
    const int l  = t & 63;
    const int lq = l >> 4;
    const int ln = l & 15;
    const int b  = blockIdx.z;
    const int h  = blockIdx.y;
    const int q0 = blockIdx.x * 64;
    const int ln7 = ln & 7;

    bf16x8 qf[2];
    {
        const ushort* qrow = Qb + ((size_t)(b*S_ + q0 + w*16 + ln))*H_ + h*HD_ + lq*8;
        qf[0] = *reinterpret_cast<const bf16x8*>(qrow);
        qf[1] = *reinterpret_cast<const bf16x8*>(qrow + 32);
    }

    bf16x8 onesb;
#pragma unroll
    for (int j = 0; j < 8; ++j) onesb[j] = (short)0x3F80;

    size_t koff[2], voff[2];
    int    dsto[2];
#pragma unroll
    for (int i = 0; i < 2; ++i) {
        const int chunk = i*256 + t;
        const int row   = chunk >> 3;
        const int c8    = (chunk & 7) ^ (row & 7);
        koff[i] = (size_t)(b*S_ + row)*H_ + h*HD_ + c8*8;
        voff[i] = ((size_t)((b*NH_ + h)*HD_ + row))*S_ + c8*8;
        dsto[i] = chunk*8;
    }

    f32x4 lsacc = f32x4{0.f, 0.f, 0.f, 0.f};
    f32x4 oacc[4];
#pragma unroll
    for (int nt = 0; nt < 4; ++nt) oacc[nt] = f32x4{0.f, 0.f, 0.f, 0.f};

    auto tile_body = [&](const ushort* __restrict__ ksb, const ushort* __restrict__ vsb,
                         int pre_kt, bool do_pre,
                         ushort* __restrict__ kdst, ushort* __restrict__ vdst) {
        if (do_pre) {
#pragma unroll
            for (int i = 0; i < 2; ++i) {
                gload_lds16(Kb + koff[i] + (size_t)pre_kt*H_, &kdst[dsto[i]]);
                gload_lds16(Vtg + voff[i] + pre_kt, &vdst[dsto[i]]);
            }
        }

        f32x4 sacc[4];
#pragma unroll
        for (int nt = 0; nt < 4; ++nt) sacc[nt] = f32x4{0.f, 0.f, 0.f, 0.f};
#pragma unroll
        for (int ks = 0; ks < 2; ++ks) {
            bf16x8 kb[4];
#pragma unroll
            for (int nt = 0; nt < 4; ++nt)
                kb[nt] = *reinterpret_cast<const bf16x8*>(
                    &ksb[(nt*16 + ln)*64 + (((ks*4 + lq) ^ ln7) * 8)]);
#pragma unroll
            for (int nt = 0; nt < 4; ++nt)
                sacc[nt] = __builtin_amdgcn_mfma_f32_16x16x32_bf16(
                    kb[nt], qf[ks], sacc[nt], 0, 0, 0);
        }

#pragma unroll
        for (int nt = 0; nt < 4; ++nt) {
            const float e0 = exp2f(sacc[nt][0]);
            const float e1 = exp2f(sacc[nt][1]);
            const float e2 = exp2f(sacc[nt][2]);
            const float e3 = exp2f(sacc[nt][3]);
            uint2 pk;
            pk.x = cvt_pk_bf16(e0, e1);
            pk.y = cvt_pk_bf16(e2, e3);
            const int wch = (nt*2 + (lq >> 1)) ^ ln7;
            *reinterpret_cast<uint2*>(&Ps[w][ln*64 + wch*8 + (lq & 1)*4]) = pk;
        }

#pragma unroll
        for (int ks = 0; ks < 2; ++ks) {
            const bf16x8 pa = *reinterpret_cast<const bf16x8*>(
                &Ps[w][ln*64 + (((ks*4 + lq) ^ ln7) * 8)]);
            lsacc = __builtin_amdgcn_mfma_f32_16x16x32_bf16(pa, onesb, lsacc, 0, 0, 0);
#pragma unroll
            for (int nt = 0; nt < 4; ++nt) {
                const bf16x8 vb8 = *reinterpret_cast<const bf16x8*>(
                    &vsb[(nt*16 + ln)*64 + (((ks*4 + lq) ^ ln7) * 8)]);
                oacc[nt] = __builtin_amdgcn_mfma_f32_16x16x32_bf16(
                    pa, vb8, oacc[nt], 0, 0, 0);
            }
        }

        __syncthreads();
    };

#pragma unroll
    for (int i = 0; i < 2; ++i) {
        gload_lds16(Kb + koff[i], &Ks0[dsto[i]]);
        gload_lds16(Vtg + voff[i], &Vs0[dsto[i]]);
    }
    __syncthreads();

    for (int kt = 0; kt < S_; kt += 128) {
        tile_body(Ks0, Vs0, kt + 64, true, Ks1, Vs1);
        tile_body(Ks1, Vs1, kt + 128, kt + 128 < S_, Ks0, Vs0);
    }

    float ivr[4];
#pragma unroll
    for (int r = 0; r < 4; ++r) ivr[r] = 1.f / lsacc[r];

    if (ln == 0) {
        float4 o;
        o.x = -__log2f(lsacc[0]);
        o.y = -__log2f(lsacc[1]);
        o.z = -__log2f(lsacc[2]);
        o.w = -__log2f(lsacc[3]);
        *reinterpret_cast<float4*>(
            il2_g + (size_t)(b*NH_ + h)*S_ + q0 + w*16 + lq*4) = o;
    }

    ushort* crow = ctx + ((size_t)(b*S_ + q0 + w*16 + lq*4))*H_ + h*HD_ + ln;
#pragma unroll
    for (int r = 0; r < 4; ++r)
#pragma unroll
        for (int nt = 0; nt < 4; ++nt)
            crow[(size_t)r*H_ + nt*16] = f2bf(oacc[nt][r] * ivr[r]);
}

// ---------------------------------------------------------------
// fused colsum + out-projection (one launch, role by block id).
// blocks [0,1024): colsum (k-tile, h, b) ; [1024,1536): GEMM BM=64.
// Shared-memory union: 32 KB.
// ---------------------------------------------------------------
struct FusedArgs {
    const ushort* Qb; const ushort* Kb;
    const float*  il2; float* colsum;
    const ushort* A;  const ushort* W;
    const float*  bias; float* Y;
};

__global__ __launch_bounds__(256) void colsum_outproj(FusedArgs fa)
{
    __shared__ __align__(16) char smem[32768];
    const int id = blockIdx.x;
    const int t  = threadIdx.x;
    const int w  = t >> 6;
    const int l  = t & 63;
    const int lq = l >> 4;
    const int ln = l & 15;
    const int ln7 = ln & 7;

    if (id < 1024) {
        // -------- colsum role --------
        ushort* KsT = (ushort*)smem;              // 8 KB
        ushort* Qs0 = (ushort*)(smem + 8192);     // 8 KB
        ushort* Qs1 = (ushort*)(smem + 16384);    // 8 KB
        float*  iv  = (float*)(smem + 24576);     // 8 KB

        const int k0 = (id & 31) * 64;
        const int h  = (id >> 5) & 15;
        const int b  = id >> 9;
        const int bh = b*NH_ + h;

        int crow_[2], cc8[2], dsto[2];
#pragma unroll
        for (int i = 0; i < 2; ++i) {
            const int chunk = i*256 + t;
            crow_[i] = chunk >> 3;
            cc8[i]   = (chunk & 7) ^ (crow_[i] & 7);
            dsto[i]  = chunk*8;
        }

#pragma unroll
        for (int i = 0; i < 2; ++i) {
            gload_lds16(fa.Kb + (size_t)(b*S_ + k0 + crow_[i])*H_ + h*HD_ + cc8[i]*8, &KsT[dsto[i]]);
            gload_lds16(fa.il2 + (size_t)bh*S_ + (i*256 + t)*4, &iv[(i*256 + t)*4]);
            gload_lds16(fa.Qb + (size_t)(b*S_ + crow_[i])*H_ + h*HD_ + cc8[i]*8, &Qs0[dsto[i]]);
        }
        __syncthreads();

        bf16x8 kf[2];
#pragma unroll
        for (int ks = 0; ks < 2; ++ks)
            kf[ks] = *reinterpret_cast<const bf16x8*>(
                &KsT[(w*16 + ln)*64 + (((ks*4 + lq) ^ ln7) * 8)]);

        float cs4[4] = {0.f, 0.f, 0.f, 0.f};

        for (int qt = 0; qt < S_; qt += 128) {
            // phase A: compute Qs0, prefetch qt+64 -> Qs1
#pragma unroll
            for (int i = 0; i < 2; ++i)
                gload_lds16(fa.Qb + (size_t)(b*S_ + qt + 64 + crow_[i])*H_ + h*HD_ + cc8[i]*8,
                            &Qs1[dsto[i]]);
#pragma unroll
            for (int c = 0; c < 4; ++c) {
                f32x4 sacc = f32x4{0.f, 0.f, 0.f, 0.f};
#pragma unroll
                for (int ks = 0; ks < 2; ++ks) {
                    const bf16x8 af = *reinterpret_cast<const bf16x8*>(
                        &Qs0[(c*16 + ln)*64 + (((ks*4 + lq) ^ ln7) * 8)]);
                    sacc = __builtin_amdgcn_mfma_f32_16x16x32_bf16(af, kf[ks], sacc, 0, 0, 0);
                }
                const f32x4 iv4 = *reinterpret_cast<const f32x4*>(&iv[qt + c*16 + lq*4]);
#pragma unroll
                for (int r = 0; r < 4; ++r)
                    cs4[r] += exp2f(sacc[r] + iv4[r]);
            }
            __syncthreads();

            // phase B: compute Qs1, prefetch qt+128 -> Qs0
            if (qt + 128 < S_) {
#pragma unroll
                for (int i = 0; i < 2; ++i)
                    gload_lds16(fa.Qb + (size_t)(b*S_ + qt + 128 + crow_[i])*H_ + h*HD_ + cc8[i]*8,
                                &Qs0[dsto[i]]);
            }
#pragma unroll
            for (int c = 0; c < 4; ++c) {
                f32x4 sacc = f32x4{0.f, 0.f, 0.f, 0.f};
#pragma unroll
                for (int ks = 0; ks < 2; ++ks) {
                    const bf16x8 af = *reinterpret_cast<const bf16x8*>(
                        &Qs1[(c*16 + ln)*64 + (((ks*4 + lq) ^ ln7) * 8)]);
                    sacc = __builtin_amdgcn_mfma_f32_16x16x32_bf16(af, kf[ks], sacc, 0, 0, 0);
                }
                const f32x4 iv4 = *reinterpret_cast<const f32x4*>(&iv[qt + 64 + c*16 + lq*4]);
#pragma unroll
                for (int r = 0; r < 4; ++r)
                    cs4[r] += exp2f(sacc[r] + iv4[r]);
            }
            __syncthreads();
        }

        float cs = (cs4[0] + cs4[1]) + (cs4[2] + cs4[3]);
        cs += __shfl_xor(cs, 16);
        cs += __shfl_xor(cs, 32);
        if (l < 16)
            atomicAdd(&fa.colsum[(size_t)b*S_ + k0 + w*16 + l], cs);
    } else {
        // -------- out-projection role (BM=64, BN=128, f32 out) --------
        ushort* As = (ushort*)smem;               // 8 KB
        ushort* Bs = (ushort*)(smem + 8192);      // 16 KB

        const int g  = id - 1024;
        const int m0 = (g & 63) * 64;
        const int n0 = (g >> 6) * 128;
        const int wr = w >> 1;
        const int wc = w & 1;
        const int srow = l >> 3;
        const int scol = (l & 7) * 8;

        f32x4 acc[2][4];
#pragma unroll
        for (int m = 0; m < 2; ++m)
#pragma unroll
            for (int n = 0; n < 4; ++n) acc[m][n] = f32x4{0.f, 0.f, 0.f, 0.f};

        for (int k0 = 0; k0 < H_; k0 += 64) {
            __syncthreads();
#pragma unroll
            for (int i = 0; i < 2; ++i) {
                const int rb = i*32 + w*8;
                gload_lds16(fa.A + (size_t)(m0 + rb + srow)*H_ + k0 + scol, &As[rb*64]);
            }
#pragma unroll
            for (int i = 0; i < 4; ++i) {
                const int rb = i*32 + w*8;
                gload_lds16(fa.W + (size_t)(n0 + rb + srow)*H_ + k0 + scol, &Bs[rb*64]);
            }
            __syncthreads();
#pragma unroll
            for (int ks = 0; ks < 2; ++ks) {
                bf16x8 bfr[4];
#pragma unroll
                for (int n = 0; n < 4; ++n)
                    bfr[n] = *reinterpret_cast<const bf16x8*>(&Bs[(wc*64 + n*16 + ln)*64 + ks*32 + lq*8]);
#pragma unroll
                for (int m = 0; m < 2; ++m) {
                    const bf16x8 afr = *reinterpret_cast<const bf16x8*>(&As[(wr*32 + m*16 + ln)*64 + ks*32 + lq*8]);
#pragma unroll
                    for (int n = 0; n < 4; ++n)
                        acc[m][n] = __builtin_amdgcn_mfma_f32_16x16x32_bf16(afr, bfr[n], acc[m][n], 0, 0, 0);
                }
            }
        }

        float bv[4];
#pragma unroll
        for (int n = 0; n < 4; ++n) bv[n] = fa.bias[n0 + wc*64 + n*16 + ln];

#pragma unroll
        for (int m = 0; m < 2; ++m) {
#pragma unroll
            for (int r = 0; r < 4; ++r) {
                const size_t row = (size_t)(m0 + wr*32 + m*16 + lq*4 + r);
#pragma unroll
                for (int n = 0; n < 4; ++n) {
                    const int col = n0 + wc*64 + n*16 + ln;
                    fa.Y[row*H_ + col] = acc[m][n][r] + bv[n];
                }
            }
        }
    }
}

__global__ void avg_write(const float* __restrict__ colsum, float* __restrict__ out, float inv)
{
    const int i = blockIdx.x * 256 + threadIdx.x;
    if (i < NTOK) out[i] = colsum[i] * inv;
}

extern "C" void kernel_launch(void* const* d_in, const int* in_sizes, int n_in,
                              void* d_out, int out_size, void* d_ws, size_t ws_size,
                              hipStream_t stream)
{
    const float* x  = (const float*)d_in[0];
    const float* Wq = (const float*)d_in[1];
    const float* bq = (const float*)d_in[2];
    const float* Wk = (const float*)d_in[3];
    const float* bk = (const float*)d_in[4];
    const float* Wv = (const float*)d_in[5];
    const float* bv = (const float*)d_in[6];
    const float* Wo = (const float*)d_in[7];
    const float* bo = (const float*)d_in[8];

    float* out     = (float*)d_out;
    float* avg_out = out + (size_t)NTOK * H_;

    char* ws = (char*)d_ws;
    const size_t mat  = (size_t)NTOK * H_ * sizeof(ushort);   // 8 MB
    const size_t wmat = (size_t)H_ * H_ * sizeof(ushort);     // 2 MB
    ushort* xb   = (ushort*)(ws);                  // also ctx (x dead after projections)
    ushort* Qb   = (ushort*)(ws + mat);
    ushort* Kb   = (ushort*)(ws + 2*mat);
    ushort* Vb   = (ushort*)(ws + 3*mat);
    ushort* Vtg  = (ushort*)(ws + 4*mat);          // V^T [(b,h)][d][s]
    ushort* Wqb  = (ushort*)(ws + 5*mat);
    ushort* Wkb  = (ushort*)(ws + 5*mat + wmat);
    ushort* Wvb  = (ushort*)(ws + 5*mat + 2*wmat);
    ushort* Wob  = (ushort*)(ws + 5*mat + 3*wmat);
    float*  colsum = (float*)(ws + 5*mat + 4*wmat);                   // 16 KB
    float*  il2    = (float*)(ws + 5*mat + 4*wmat + 64*1024);         // 256 KB
    ushort* ctxb = xb;

    const dim3 blk(256);

    // 1) all converts + colsum zero, one launch
    {
        PrepArgs pa;
        pa.src[0] = x;  pa.dst[0] = xb;
        pa.src[1] = Wq; pa.dst[1] = Wqb;
        pa.src[2] = Wk; pa.dst[2] = Wkb;
        pa.src[3] = Wv; pa.dst[3] = Wvb;
        pa.src[4] = Wo; pa.dst[4] = Wob;
        pa.zero = colsum;
        prep<<<dim3(4112), blk, 0, stream>>>(pa);
    }

    // 2) fused QKV projections (Q pre-scaled by SC2)
    {
        GemmArgs ga;
        ga.W[0] = Wqb; ga.W[1] = Wkb; ga.W[2] = Wvb;
        ga.bias[0] = bq; ga.bias[1] = bk; ga.bias[2] = bv;
        ga.Y[0] = Qb; ga.Y[1] = Kb; ga.Y[2] = Vb;
        ga.scale[0] = SC2; ga.scale[1] = 1.f; ga.scale[2] = 1.f;
        gemm_qkv<<<dim3(NTOK/128, H_/128, 3), blk, 0, stream>>>(xb, ga, NTOK, H_, H_);
    }

    // 3) V transpose
    transpose_v<<<dim3(S_/64, NH_, B_), blk, 0, stream>>>(Vb, Vtg);

    // 4) PV sweep (writes ctx + il2)
    attn_pv<<<dim3(S_/64, NH_, B_), blk, 0, stream>>>(Qb, Kb, Vtg, ctxb, il2);

    // 5) colsum || out-projection (one launch, role-split grid)
    {
        FusedArgs fa;
        fa.Qb = Qb; fa.Kb = Kb; fa.il2 = il2; fa.colsum = colsum;
        fa.A = ctxb; fa.W = Wob; fa.bias = bo; fa.Y = out;
        colsum_outproj<<<dim3(1536), blk, 0, stream>>>(fa);
    }

    // 6) avg write
    avg_write<<<dim3((NTOK + 255)/256), blk, 0, stream>>>(colsum, avg_out, 1.f/((float)NH_ * (float)S_));
}

// Round 11
// 180.459 us; speedup vs baseline: 1.1702x; 1.0140x over previous
//
#include <hip/hip_runtime.h>
#include <hip/hip_bf16.h>

#define B_  2
#define S_  2048
#define H_  1024
#define NH_ 16
#define HD_ 64
#define NTOK (B_*S_)   // 4096

typedef __attribute__((ext_vector_type(8))) short bf16x8;
typedef __attribute__((ext_vector_type(4))) float f32x4;

#define SC2 0.18033688011112042f   // (1/sqrt(64)) * log2(e)
#define AVGINV (1.f/((float)NH_*(float)S_))

static __device__ __forceinline__ ushort f2bf(float f) {
    __hip_bfloat16 h = __float2bfloat16(f);
    return *reinterpret_cast<ushort*>(&h);
}
static __device__ __forceinline__ uint cvt_pk_bf16(float lo, float hi) {
    uint r;
    asm("v_cvt_pk_bf16_f32 %0, %1, %2" : "=v"(r) : "v"(lo), "v"(hi));
    return r;
}

static __device__ __forceinline__ void gload_lds16(const void* g, void* l) {
    __builtin_amdgcn_global_load_lds(
        (const __attribute__((address_space(1))) void*)g,
        (__attribute__((address_space(3))) void*)l,
        16, 0, 0);
}

// ---------------------------------------------------------------
// prep: all f32->bf16 converts + avg_out zero in ONE launch.
// ---------------------------------------------------------------
struct PrepArgs {
    const float* src[5];   // x, Wq, Wk, Wv, Wo
    ushort*      dst[5];
    float*       zero;     // avg_out
};

static __device__ __forceinline__ void conv8(const float* __restrict__ s,
                                             ushort* __restrict__ d, int i)
{
    const float4 a = reinterpret_cast<const float4*>(s)[2*i + 0];
    const float4 b = reinterpret_cast<const float4*>(s)[2*i + 1];
    ushort u[8];
    u[0] = f2bf(a.x); u[1] = f2bf(a.y); u[2] = f2bf(a.z); u[3] = f2bf(a.w);
    u[4] = f2bf(b.x); u[5] = f2bf(b.y); u[6] = f2bf(b.z); u[7] = f2bf(b.w);
    reinterpret_cast<uint4*>(d)[i] = *reinterpret_cast<uint4*>(u);
}

__global__ __launch_bounds__(256) void prep(PrepArgs a)
{
    int bid = blockIdx.x;
    const int t = threadIdx.x;
    if (bid < 2048) {                      // x: 524288 chunks
        conv8(a.src[0], a.dst[0], bid*256 + t);
        return;
    }
    bid -= 2048;
    if (bid < 2048) {                      // weights: 131072 chunks each
        const int wi = 1 + (bid >> 9);
        const int i  = (bid & 511)*256 + t;
        conv8(a.src[wi], a.dst[wi], i);
        return;
    }
    bid -= 2048;                           // zero avg_out (16 blocks)
    const int i = bid*256 + t;
    if (i < NTOK) a.zero[i] = 0.f;
}

// ---------------------------------------------------------------
// V [tok][H] bf16 -> Vt [(b*NH+h)][d][s] bf16
// ---------------------------------------------------------------
__global__ __launch_bounds__(256) void transpose_v(
    const ushort* __restrict__ Vb, ushort* __restrict__ Vt)
{
    __shared__ ushort T[64][72];
    const int t  = threadIdx.x;
    const int b  = blockIdx.z;
    const int h  = blockIdx.y;
    const int s0 = blockIdx.x * 64;
    const int r  = t >> 2;
    const int c0 = (t & 3) * 16;

    const ushort* src = Vb + (size_t)(b*S_ + s0 + r)*H_ + h*HD_ + c0;
    *reinterpret_cast<uint4*>(&T[r][c0])     = *reinterpret_cast<const uint4*>(src);
    *reinterpret_cast<uint4*>(&T[r][c0 + 8]) = *reinterpret_cast<const uint4*>(src + 8);
    __syncthreads();

    const int d = r;
    ushort tmp[16];
#pragma unroll
    for (int k = 0; k < 16; ++k) tmp[k] = T[c0 + k][d];
    ushort* dst = Vt + ((size_t)((b*NH_ + h)*HD_ + d))*S_ + s0 + c0;
    *reinterpret_cast<uint4*>(dst)     = *reinterpret_cast<uint4*>(&tmp[0]);
    *reinterpret_cast<uint4*>(dst + 8) = *reinterpret_cast<uint4*>(&tmp[8]);
}

// ---------------------------------------------------------------
// MFMA GEMM (QKV, fused over z): Y = (A @ W^T + bias) * scale, bf16 out
// ---------------------------------------------------------------
struct GemmArgs {
    const ushort* W[3];
    const float*  bias[3];
    void*         Y[3];
    float         scale[3];
};

__global__ __launch_bounds__(256) void gemm_qkv(
    const ushort* __restrict__ A, GemmArgs args, int M, int N, int K)
{
    constexpr int MREP = 4;
    constexpr int BM = MREP * 32;
    __shared__ __align__(16) ushort As[BM * 64];
    __shared__ __align__(16) ushort Bs[128 * 64];

    const int z = blockIdx.z;
    const ushort* __restrict__ W   = args.W[z];
    const float*  __restrict__ bia = args.bias[z];
    const float sc = args.scale[z];

    const int t  = threadIdx.x;
    const int w  = t >> 6;
    const int l  = t & 63;
    const int lq = l >> 4;
    const int ln = l & 15;
    const int wr = w >> 1;
    const int wc = w & 1;
    const int m0 = blockIdx.x * BM;
    const int n0 = blockIdx.y * 128;
    const int srow = l >> 3;
    const int scol = (l & 7) * 8;

    f32x4 acc[MREP][4];
#pragma unroll
    for (int m = 0; m < MREP; ++m)
#pragma unroll
        for (int n = 0; n < 4; ++n) acc[m][n] = f32x4{0.f, 0.f, 0.f, 0.f};

    for (int k0 = 0; k0 < K; k0 += 64) {
        __syncthreads();
#pragma unroll
        for (int i = 0; i < BM/32; ++i) {
            const int rb = i*32 + w*8;
            gload_lds16(A + (size_t)(m0 + rb + srow)*K + k0 + scol, &As[rb*64]);
        }
#pragma unroll
        for (int i = 0; i < 4; ++i) {
            const int rb = i*32 + w*8;
            gload_lds16(W + (size_t)(n0 + rb + srow)*K + k0 + scol, &Bs[rb*64]);
        }
        __syncthreads();
#pragma unroll
        for (int ks = 0; ks < 2; ++ks) {
            bf16x8 bfr[4];
#pragma unroll
            for (int n = 0; n < 4; ++n)
                bfr[n] = *reinterpret_cast<const bf16x8*>(&Bs[(wc*64 + n*16 + ln)*64 + ks*32 + lq*8]);
#pragma unroll
            for (int m = 0; m < MREP; ++m) {
                const bf16x8 afr = *reinterpret_cast<const bf16x8*>(&As[(wr*MREP*16 + m*16 + ln)*64 + ks*32 + lq*8]);
#pragma unroll
                for (int n = 0; n < 4; ++n)
                    acc[m][n] = __builtin_amdgcn_mfma_f32_16x16x32_bf16(afr, bfr[n], acc[m][n], 0, 0, 0);
            }
        }
    }

    float bv[4];
#pragma unroll
    for (int n = 0; n < 4; ++n) bv[n] = bia[n0 + wc*64 + n*16 + ln];

    ushort* Y = (ushort*)args.Y[z];
#pragma unroll
    for (int m = 0; m < MREP; ++m) {
#pragma unroll
        for (int r = 0; r < 4; ++r) {
            const size_t row = (size_t)(m0 + wr*MREP*16 + m*16 + lq*4 + r);
#pragma unroll
            for (int n = 0; n < 4; ++n) {
                const int col = n0 + wc*64 + n*16 + ln;
                Y[row*N + col] = f2bf((acc[m][n][r] + bv[n]) * sc);
            }
        }
    }
}

// ---------------------------------------------------------------
// attn_pv (round 11): as round 9/10 plus:
//  - XCD swizzle: 1D grid, id = (bh&7) + 8*qtile + 256*(bh>>3)
//    -> all 32 q-blocks of one (b,h) land on ONE XCD's L2.
//  - zero-C MFMA init (no per-tile v_mov zeroing of sacc)
// ---------------------------------------------------------------
__global__ __launch_bounds__(256) void attn_pv(
    const ushort* __restrict__ Qb, const ushort* __restrict__ Kb,
    const ushort* __restrict__ Vtg, ushort* __restrict__ ctx,
    float* __restrict__ il2_g)
{
    __shared__ __align__(16) ushort Ks0[64*64];
    __shared__ __align__(16) ushort Ks1[64*64];
    __shared__ __align__(16) ushort Vs0[64*64];
    __shared__ __align__(16) ushort Vs1[64*64];
    __shared__ __align__(16) ushort Ps[4][16*64];   // per-wave P, XOR-swizzled

    const int id = blockIdx.x;
    const int qt_ = (id >> 3) & 31;
    const int bh  = (id & 7) + ((id >> 8) << 3);
    const int b   = bh >> 4;
    const int h   = bh & 15;
    const int q0  = qt_ * 64;

    const int t  = threadIdx.x;
    const int w  = t >> 6;
    const int l  = t & 63;
    const int lq = l >> 4;
    const int ln = l & 15;
    const int ln7 = ln & 7;

    bf16x8 qf[2];
    {
        const ushort* qrow = Qb + ((size_t)(b*S_ + q0 + w*16 + ln))*H_ + h*HD_ + lq*8;
        qf[0] = *reinterpret_cast<const bf16x8*>(qrow);
        qf[1] = *reinterpret_cast<const bf16x8*>(qrow + 32);
    }

    bf16x8 onesb;
#pragma unroll
    for (int j = 0; j < 8; ++j) onesb[j] = (short)0x3F80;

    const f32x4 ZED = f32x4{0.f, 0.f, 0.f, 0.f};

    size_t koff[2], voff[2];
    int    dsto[2];
#pragma unroll
    for (int i = 0; i < 2; ++i) {
        const int chunk = i*256 + t;
        const int row   = chunk >> 3;
        const int c8    = (chunk & 7) ^ (row & 7);
        koff[i] = (size_t)(b*S_ + row)*H_ + h*HD_ + c8*8;
        voff[i] = ((size_t)((b*NH_ + h)*HD_ + row))*S_ + c8*8;
        dsto[i] = chunk*8;
    }

    f32x4 lsacc = ZED;
    f32x4 oacc[4];
#pragma unroll
    for (int nt = 0; nt < 4; ++nt) oacc[nt] = ZED;

    auto tile_body = [&](const ushort* __restrict__ ksb, const ushort* __restrict__ vsb,
                         int pre_kt, bool do_pre,
                         ushort* __restrict__ kdst, ushort* __restrict__ vdst) {
        if (do_pre) {
#pragma unroll
            for (int i = 0; i < 2; ++i) {
                gload_lds16(Kb + koff[i] + (size_t)pre_kt*H_, &kdst[dsto[i]]);
                gload_lds16(Vtg + voff[i] + pre_kt, &vdst[dsto[i]]);
            }
        }

        // swapped QK^T, zero-C init (ks=0), accumulate (ks=1)
        f32x4 sacc[4];
        {
            bf16x8 kb[4];
#pragma unroll
            for (int nt = 0; nt < 4; ++nt)
                kb[nt] = *reinterpret_cast<const bf16x8*>(
                    &ksb[(nt*16 + ln)*64 + ((lq ^ ln7) * 8)]);
#pragma unroll
            for (int nt = 0; nt < 4; ++nt)
                sacc[nt] = __builtin_amdgcn_mfma_f32_16x16x32_bf16(
                    kb[nt], qf[0], ZED, 0, 0, 0);
        }
        {
            bf16x8 kb[4];
#pragma unroll
            for (int nt = 0; nt < 4; ++nt)
                kb[nt] = *reinterpret_cast<const bf16x8*>(
                    &ksb[(nt*16 + ln)*64 + (((4 + lq) ^ ln7) * 8)]);
#pragma unroll
            for (int nt = 0; nt < 4; ++nt)
                sacc[nt] = __builtin_amdgcn_mfma_f32_16x16x32_bf16(
                    kb[nt], qf[1], sacc[nt], 0, 0, 0);
        }

#pragma unroll
        for (int nt = 0; nt < 4; ++nt) {
            const float e0 = exp2f(sacc[nt][0]);
            const float e1 = exp2f(sacc[nt][1]);
            const float e2 = exp2f(sacc[nt][2]);
            const float e3 = exp2f(sacc[nt][3]);
            uint2 pk;
            pk.x = cvt_pk_bf16(e0, e1);
            pk.y = cvt_pk_bf16(e2, e3);
            const int wch = (nt*2 + (lq >> 1)) ^ ln7;
            *reinterpret_cast<uint2*>(&Ps[w][ln*64 + wch*8 + (lq & 1)*4]) = pk;
        }

#pragma unroll
        for (int ks = 0; ks < 2; ++ks) {
            const bf16x8 pa = *reinterpret_cast<const bf16x8*>(
                &Ps[w][ln*64 + (((ks*4 + lq) ^ ln7) * 8)]);
            lsacc = __builtin_amdgcn_mfma_f32_16x16x32_bf16(pa, onesb, lsacc, 0, 0, 0);
#pragma unroll
            for (int nt = 0; nt < 4; ++nt) {
                const bf16x8 vb8 = *reinterpret_cast<const bf16x8*>(
                    &vsb[(nt*16 + ln)*64 + (((ks*4 + lq) ^ ln7) * 8)]);
                oacc[nt] = __builtin_amdgcn_mfma_f32_16x16x32_bf16(
                    pa, vb8, oacc[nt], 0, 0, 0);
            }
        }

        __syncthreads();
    };

#pragma unroll
    for (int i = 0; i < 2; ++i) {
        gload_lds16(Kb + koff[i], &Ks0[dsto[i]]);
        gload_lds16(Vtg + voff[i], &Vs0[dsto[i]]);
    }
    __syncthreads();

    for (int kt = 0; kt < S_; kt += 128) {
        tile_body(Ks0, Vs0, kt + 64, true, Ks1, Vs1);
        tile_body(Ks1, Vs1, kt + 128, kt + 128 < S_, Ks0, Vs0);
    }

    float ivr[4];
#pragma unroll
    for (int r = 0; r < 4; ++r) ivr[r] = 1.f / lsacc[r];

    if (ln == 0) {
        float4 o;
        o.x = -__log2f(lsacc[0]);
        o.y = -__log2f(lsacc[1]);
        o.z = -__log2f(lsacc[2]);
        o.w = -__log2f(lsacc[3]);
        *reinterpret_cast<float4*>(
            il2_g + (size_t)(b*NH_ + h)*S_ + q0 + w*16 + lq*4) = o;
    }

    ushort* crow = ctx + ((size_t)(b*S_ + q0 + w*16 + lq*4))*H_ + h*HD_ + ln;
#pragma unroll
    for (int r = 0; r < 4; ++r)
#pragma unroll
        for (int nt = 0; nt < 4; ++nt)
            crow[(size_t)r*H_ + nt*16] = f2bf(oacc[nt][r] * ivr[r]);
}

// ---------------------------------------------------------------
// fused colsum + out-projection. blocks [0,1024): colsum with XCD
// swizzle (id = (bh&7) + 8*ktile + 256*(bh>>3)); [1024,1536): GEMM.
// colsum accumulates normalized values directly into avg_out.
// ---------------------------------------------------------------
struct FusedArgs {
    const ushort* Qb; const ushort* Kb;
    const float*  il2; float* avg_out;
    const ushort* A;  const ushort* W;
    const float*  bias; float* Y;
};

__global__ __launch_bounds__(256) void colsum_outproj(FusedArgs fa)
{
    __shared__ __align__(16) char smem[32768];
    const int id = blockIdx.x;
    const int t  = threadIdx.x;
    const int w  = t >> 6;
    const int l  = t & 63;
    const int lq = l >> 4;
    const int ln = l & 15;
    const int ln7 = ln & 7;
    const f32x4 ZED = f32x4{0.f, 0.f, 0.f, 0.f};

    if (id < 1024) {
        // -------- colsum role (XCD-swizzled) --------
        ushort* KsT = (ushort*)smem;              // 8 KB
        ushort* Qs0 = (ushort*)(smem + 8192);     // 8 KB
        ushort* Qs1 = (ushort*)(smem + 16384);    // 8 KB
        float*  iv  = (float*)(smem + 24576);     // 8 KB

        const int kt_ = (id >> 3) & 31;
        const int bh  = (id & 7) + ((id >> 8) << 3);
        const int b   = bh >> 4;
        const int h   = bh & 15;
        const int k0  = kt_ * 64;

        int crow_[2], cc8[2], dsto[2];
#pragma unroll
        for (int i = 0; i < 2; ++i) {
            const int chunk = i*256 + t;
            crow_[i] = chunk >> 3;
            cc8[i]   = (chunk & 7) ^ (crow_[i] & 7);
            dsto[i]  = chunk*8;
        }

#pragma unroll
        for (int i = 0; i < 2; ++i) {
            gload_lds16(fa.Kb + (size_t)(b*S_ + k0 + crow_[i])*H_ + h*HD_ + cc8[i]*8, &KsT[dsto[i]]);
            gload_lds16(fa.il2 + (size_t)bh*S_ + (i*256 + t)*4, &iv[(i*256 + t)*4]);
            gload_lds16(fa.Qb + (size_t)(b*S_ + crow_[i])*H_ + h*HD_ + cc8[i]*8, &Qs0[dsto[i]]);
        }
        __syncthreads();

        bf16x8 kf[2];
#pragma unroll
        for (int ks = 0; ks < 2; ++ks)
            kf[ks] = *reinterpret_cast<const bf16x8*>(
                &KsT[(w*16 + ln)*64 + (((ks*4 + lq) ^ ln7) * 8)]);

        float cs4[4] = {0.f, 0.f, 0.f, 0.f};

        for (int qt = 0; qt < S_; qt += 128) {
#pragma unroll
            for (int i = 0; i < 2; ++i)
                gload_lds16(fa.Qb + (size_t)(b*S_ + qt + 64 + crow_[i])*H_ + h*HD_ + cc8[i]*8,
                            &Qs1[dsto[i]]);
#pragma unroll
            for (int c = 0; c < 4; ++c) {
                const bf16x8 a0 = *reinterpret_cast<const bf16x8*>(
                    &Qs0[(c*16 + ln)*64 + ((lq ^ ln7) * 8)]);
                const bf16x8 a1 = *reinterpret_cast<const bf16x8*>(
                    &Qs0[(c*16 + ln)*64 + (((4 + lq) ^ ln7) * 8)]);
                f32x4 sacc = __builtin_amdgcn_mfma_f32_16x16x32_bf16(a0, kf[0], ZED, 0, 0, 0);
                sacc = __builtin_amdgcn_mfma_f32_16x16x32_bf16(a1, kf[1], sacc, 0, 0, 0);
                const f32x4 iv4 = *reinterpret_cast<const f32x4*>(&iv[qt + c*16 + lq*4]);
#pragma unroll
                for (int r = 0; r < 4; ++r)
                    cs4[r] += exp2f(sacc[r] + iv4[r]);
            }
            __syncthreads();

            if (qt + 128 < S_) {
#pragma unroll
                for (int i = 0; i < 2; ++i)
                    gload_lds16(fa.Qb + (size_t)(b*S_ + qt + 128 + crow_[i])*H_ + h*HD_ + cc8[i]*8,
                                &Qs0[dsto[i]]);
            }
#pragma unroll
            for (int c = 0; c < 4; ++c) {
                const bf16x8 a0 = *reinterpret_cast<const bf16x8*>(
                    &Qs1[(c*16 + ln)*64 + ((lq ^ ln7) * 8)]);
                const bf16x8 a1 = *reinterpret_cast<const bf16x8*>(
                    &Qs1[(c*16 + ln)*64 + (((4 + lq) ^ ln7) * 8)]);
                f32x4 sacc = __builtin_amdgcn_mfma_f32_16x16x32_bf16(a0, kf[0], ZED, 0, 0, 0);
                sacc = __builtin_amdgcn_mfma_f32_16x16x32_bf16(a1, kf[1], sacc, 0, 0, 0);
                const f32x4 iv4 = *reinterpret_cast<const f32x4*>(&iv[qt + 64 + c*16 + lq*4]);
#pragma unroll
                for (int r = 0; r < 4; ++r)
                    cs4[r] += exp2f(sacc[r] + iv4[r]);
            }
            __syncthreads();
        }

        float cs = (cs4[0] + cs4[1]) + (cs4[2] + cs4[3]);
        cs += __shfl_xor(cs, 16);
        cs += __shfl_xor(cs, 32);
        if (l < 16)
            atomicAdd(&fa.avg_out[(size_t)b*S_ + k0 + w*16 + l], cs * AVGINV);
    } else {
        // -------- out-projection role (BM=64, BN=128, f32 out) --------
        ushort* As = (ushort*)smem;               // 8 KB
        ushort* Bs = (ushort*)(smem + 8192);      // 16 KB

        const int g  = id - 1024;
        const int m0 = (g & 63) * 64;
        const int n0 = (g >> 6) * 128;
        const int wr = w >> 1;
        const int wc = w & 1;
        const int srow = l >> 3;
        const int scol = (l & 7) * 8;

        f32x4 acc[2][4];
#pragma unroll
        for (int m = 0; m < 2; ++m)
#pragma unroll
            for (int n = 0; n < 4; ++n) acc[m][n] = ZED;

        for (int k0 = 0; k0 < H_; k0 += 64) {
            __syncthreads();
#pragma unroll
            for (int i = 0; i < 2; ++i) {
                const int rb = i*32 + w*8;
                gload_lds16(fa.A + (size_t)(m0 + rb + srow)*H_ + k0 + scol, &As[rb*64]);
            }
#pragma unroll
            for (int i = 0; i < 4; ++i) {
                const int rb = i*32 + w*8;
                gload_lds16(fa.W + (size_t)(n0 + rb + srow)*H_ + k0 + scol, &Bs[rb*64]);
            }
            __syncthreads();
#pragma unroll
            for (int ks = 0; ks < 2; ++ks) {
                bf16x8 bfr[4];
#pragma unroll
                for (int n = 0; n < 4; ++n)
                    bfr[n] = *reinterpret_cast<const bf16x8*>(&Bs[(wc*64 + n*16 + ln)*64 + ks*32 + lq*8]);
#pragma unroll
                for (int m = 0; m < 2; ++m) {
                    const bf16x8 afr = *reinterpret_cast<const bf16x8*>(&As[(wr*32 + m*16 + ln)*64 + ks*32 + lq*8]);
#pragma unroll
                    for (int n = 0; n < 4; ++n)
                        acc[m][n] = __builtin_amdgcn_mfma_f32_16x16x32_bf16(afr, bfr[n], acc[m][n], 0, 0, 0);
                }
            }
        }

        float bv[4];
#pragma unroll
        for (int n = 0; n < 4; ++n) bv[n] = fa.bias[n0 + wc*64 + n*16 + ln];

#pragma unroll
        for (int m = 0; m < 2; ++m) {
#pragma unroll
            for (int r = 0; r < 4; ++r) {
                const size_t row = (size_t)(m0 + wr*32 + m*16 + lq*4 + r);
#pragma unroll
                for (int n = 0; n < 4; ++n) {
                    const int col = n0 + wc*64 + n*16 + ln;
                    fa.Y[row*H_ + col] = acc[m][n][r] + bv[n];
                }
            }
        }
    }
}

extern "C" void kernel_launch(void* const* d_in, const int* in_sizes, int n_in,
                              void* d_out, int out_size, void* d_ws, size_t ws_size,
                              hipStream_t stream)
{
    const float* x  = (const float*)d_in[0];
    const float* Wq = (const float*)d_in[1];
    const float* bq = (const float*)d_in[2];
    const float* Wk = (const float*)d_in[3];
    const float* bk = (const float*)d_in[4];
    const float* Wv = (const float*)d_in[5];
    const float* bv = (const float*)d_in[6];
    const float* Wo = (const float*)d_in[7];
    const float* bo = (const float*)d_in[8];

    float* out     = (float*)d_out;
    float* avg_out = out + (size_t)NTOK * H_;

    char* ws = (char*)d_ws;
    const size_t mat  = (size_t)NTOK * H_ * sizeof(ushort);   // 8 MB
    const size_t wmat = (size_t)H_ * H_ * sizeof(ushort);     // 2 MB
    ushort* xb   = (ushort*)(ws);                  // also ctx (x dead after projections)
    ushort* Qb   = (ushort*)(ws + mat);
    ushort* Kb   = (ushort*)(ws + 2*mat);
    ushort* Vb   = (ushort*)(ws + 3*mat);
    ushort* Vtg  = (ushort*)(ws + 4*mat);          // V^T [(b,h)][d][s]
    ushort* Wqb  = (ushort*)(ws + 5*mat);
    ushort* Wkb  = (ushort*)(ws + 5*mat + wmat);
    ushort* Wvb  = (ushort*)(ws + 5*mat + 2*wmat);
    ushort* Wob  = (ushort*)(ws + 5*mat + 3*wmat);
    float*  il2  = (float*)(ws + 5*mat + 4*wmat);              // 256 KB
    ushort* ctxb = xb;

    const dim3 blk(256);

    // 1) all converts + avg_out zero, one launch
    {
        PrepArgs pa;
        pa.src[0] = x;  pa.dst[0] = xb;
        pa.src[1] = Wq; pa.dst[1] = Wqb;
        pa.src[2] = Wk; pa.dst[2] = Wkb;
        pa.src[3] = Wv; pa.dst[3] = Wvb;
        pa.src[4] = Wo; pa.dst[4] = Wob;
        pa.zero = avg_out;
        prep<<<dim3(4112), blk, 0, stream>>>(pa);
    }

    // 2) fused QKV projections (Q pre-scaled by SC2)
    {
        GemmArgs ga;
        ga.W[0] = Wqb; ga.W[1] = Wkb; ga.W[2] = Wvb;
        ga.bias[0] = bq; ga.bias[1] = bk; ga.bias[2] = bv;
        ga.Y[0] = Qb; ga.Y[1] = Kb; ga.Y[2] = Vb;
        ga.scale[0] = SC2; ga.scale[1] = 1.f; ga.scale[2] = 1.f;
        gemm_qkv<<<dim3(NTOK/128, H_/128, 3), blk, 0, stream>>>(xb, ga, NTOK, H_, H_);
    }

    // 3) V transpose
    transpose_v<<<dim3(S_/64, NH_, B_), blk, 0, stream>>>(Vb, Vtg);

    // 4) PV sweep (writes ctx + il2), XCD-swizzled 1D grid
    attn_pv<<<dim3(1024), blk, 0, stream>>>(Qb, Kb, Vtg, ctxb, il2);

    // 5) colsum (direct avg accumulate) || out-projection
    {
        FusedArgs fa;
        fa.Qb = Qb; fa.Kb = Kb; fa.il2 = il2; fa.avg_out = avg_out;
        fa.A = ctxb; fa.W = Wob; fa.bias = bo; fa.Y = out;
        colsum_outproj<<<dim3(1536), blk, 0, stream>>>(fa);
    }
}

// Round 12
// 170.848 us; speedup vs baseline: 1.2360x; 1.0563x over previous
//
#include <hip/hip_runtime.h>
#include <hip/hip_bf16.h>

#define B_  2
#define S_  2048
#define H_  1024
#define NH_ 16
#define HD_ 64
#define NTOK (B_*S_)   // 4096

typedef __attribute__((ext_vector_type(8))) short bf16x8;
typedef __attribute__((ext_vector_type(4))) float f32x4;

#define SC2 0.18033688011112042f   // (1/sqrt(64)) * log2(e)
#define AVGINV (1.f/((float)NH_*(float)S_))

static __device__ __forceinline__ ushort f2bf(float f) {
    __hip_bfloat16 h = __float2bfloat16(f);
    return *reinterpret_cast<ushort*>(&h);
}
static __device__ __forceinline__ uint cvt_pk_bf16(float lo, float hi) {
    uint r;
    asm("v_cvt_pk_bf16_f32 %0, %1, %2" : "=v"(r) : "v"(lo), "v"(hi));
    return r;
}

static __device__ __forceinline__ void gload_lds16(const void* g, void* l) {
    __builtin_amdgcn_global_load_lds(
        (const __attribute__((address_space(1))) void*)g,
        (__attribute__((address_space(3))) void*)l,
        16, 0, 0);
}

// ---------------------------------------------------------------
// prep: all f32->bf16 converts + avg_out zero in ONE launch.
// ---------------------------------------------------------------
struct PrepArgs {
    const float* src[5];   // x, Wq, Wk, Wv, Wo
    ushort*      dst[5];
    float*       zero;     // avg_out
};

static __device__ __forceinline__ void conv8(const float* __restrict__ s,
                                             ushort* __restrict__ d, int i)
{
    const float4 a = reinterpret_cast<const float4*>(s)[2*i + 0];
    const float4 b = reinterpret_cast<const float4*>(s)[2*i + 1];
    ushort u[8];
    u[0] = f2bf(a.x); u[1] = f2bf(a.y); u[2] = f2bf(a.z); u[3] = f2bf(a.w);
    u[4] = f2bf(b.x); u[5] = f2bf(b.y); u[6] = f2bf(b.z); u[7] = f2bf(b.w);
    reinterpret_cast<uint4*>(d)[i] = *reinterpret_cast<uint4*>(u);
}

__global__ __launch_bounds__(256) void prep(PrepArgs a)
{
    int bid = blockIdx.x;
    const int t = threadIdx.x;
    if (bid < 2048) {                      // x: 524288 chunks
        conv8(a.src[0], a.dst[0], bid*256 + t);
        return;
    }
    bid -= 2048;
    if (bid < 2048) {                      // weights: 131072 chunks each
        const int wi = 1 + (bid >> 9);
        const int i  = (bid & 511)*256 + t;
        conv8(a.src[wi], a.dst[wi], i);
        return;
    }
    bid -= 2048;                           // zero avg_out (16 blocks)
    const int i = bid*256 + t;
    if (i < NTOK) a.zero[i] = 0.f;
}

// ---------------------------------------------------------------
// V [tok][H] bf16 -> Vt [(b*NH+h)][d][s] bf16
// ---------------------------------------------------------------
__global__ __launch_bounds__(256) void transpose_v(
    const ushort* __restrict__ Vb, ushort* __restrict__ Vt)
{
    __shared__ ushort T[64][72];
    const int t  = threadIdx.x;
    const int b  = blockIdx.z;
    const int h  = blockIdx.y;
    const int s0 = blockIdx.x * 64;
    const int r  = t >> 2;
    const int c0 = (t & 3) * 16;

    const ushort* src = Vb + (size_t)(b*S_ + s0 + r)*H_ + h*HD_ + c0;
    *reinterpret_cast<uint4*>(&T[r][c0])     = *reinterpret_cast<const uint4*>(src);
    *reinterpret_cast<uint4*>(&T[r][c0 + 8]) = *reinterpret_cast<const uint4*>(src + 8);
    __syncthreads();

    const int d = r;
    ushort tmp[16];
#pragma unroll
    for (int k = 0; k < 16; ++k) tmp[k] = T[c0 + k][d];
    ushort* dst = Vt + ((size_t)((b*NH_ + h)*HD_ + d))*S_ + s0 + c0;
    *reinterpret_cast<uint4*>(dst)     = *reinterpret_cast<uint4*>(&tmp[0]);
    *reinterpret_cast<uint4*>(dst + 8) = *reinterpret_cast<uint4*>(&tmp[8]);
}

// ---------------------------------------------------------------
// MFMA GEMM (QKV, fused over z): Y = (A @ W^T + bias) * scale, bf16 out
// ---------------------------------------------------------------
struct GemmArgs {
    const ushort* W[3];
    const float*  bias[3];
    void*         Y[3];
    float         scale[3];
};

__global__ __launch_bounds__(256) void gemm_qkv(
    const ushort* __restrict__ A, GemmArgs args, int M, int N, int K)
{
    constexpr int MREP = 4;
    constexpr int BM = MREP * 32;
    __shared__ __align__(16) ushort As[BM * 64];
    __shared__ __align__(16) ushort Bs[128 * 64];

    const int z = blockIdx.z;
    const ushort* __restrict__ W   = args.W[z];
    const float*  __restrict__ bia = args.bias[z];
    const float sc = args.scale[z];

    const int t  = threadIdx.x;
    const int w  = t >> 6;
    const int l  = t & 63;
    const int lq = l >> 4;
    const int ln = l & 15;
    const int wr = w >> 1;
    const int wc = w & 1;
    const int m0 = blockIdx.x * BM;
    const int n0 = blockIdx.y * 128;
    const int srow = l >> 3;
    const int scol = (l & 7) * 8;

    f32x4 acc[MREP][4];
#pragma unroll
    for (int m = 0; m < MREP; ++m)
#pragma unroll
        for (int n = 0; n < 4; ++n) acc[m][n] = f32x4{0.f, 0.f, 0.f, 0.f};

    for (int k0 = 0; k0 < K; k0 += 64) {
        __syncthreads();
#pragma unroll
        for (int i = 0; i < BM/32; ++i) {
            const int rb = i*32 + w*8;
            gload_lds16(A + (size_t)(m0 + rb + srow)*K + k0 + scol, &As[rb*64]);
        }
#pragma unroll
        for (int i = 0; i < 4; ++i) {
            const int rb = i*32 + w*8;
            gload_lds16(W + (size_t)(n0 + rb + srow)*K + k0 + scol, &Bs[rb*64]);
        }
        __syncthreads();
#pragma unroll
        for (int ks = 0; ks < 2; ++ks) {
            bf16x8 bfr[4];
#pragma unroll
            for (int n = 0; n < 4; ++n)
                bfr[n] = *reinterpret_cast<const bf16x8*>(&Bs[(wc*64 + n*16 + ln)*64 + ks*32 + lq*8]);
#pragma unroll
            for (int m = 0; m < MREP; ++m) {
                const bf16x8 afr = *reinterpret_cast<const bf16x8*>(&As[(wr*MREP*16 + m*16 + ln)*64 + ks*32 + lq*8]);
#pragma unroll
                for (int n = 0; n < 4; ++n)
                    acc[m][n] = __builtin_amdgcn_mfma_f32_16x16x32_bf16(afr, bfr[n], acc[m][n], 0, 0, 0);
            }
        }
    }

    float bv[4];
#pragma unroll
    for (int n = 0; n < 4; ++n) bv[n] = bia[n0 + wc*64 + n*16 + ln];

    ushort* Y = (ushort*)args.Y[z];
#pragma unroll
    for (int m = 0; m < MREP; ++m) {
#pragma unroll
        for (int r = 0; r < 4; ++r) {
            const size_t row = (size_t)(m0 + wr*MREP*16 + m*16 + lq*4 + r);
#pragma unroll
            for (int n = 0; n < 4; ++n) {
                const int col = n0 + wc*64 + n*16 + ln;
                Y[row*N + col] = f2bf((acc[m][n][r] + bv[n]) * sc);
            }
        }
    }
}

// ---------------------------------------------------------------
// attn_pv (round 12): QB=128 — each wave owns 32 q-rows (2 subtiles
// of 16). K/V fragment reads (8+8 b128/tile) now serve 2x the MFMAs
// -> LDS traffic per q-row nearly halves (LDS was the bound, r11).
// All r9-r11 refinements kept: swizzled Ps, packed b64 P-stores,
// pre-scaled Q, ones-MFMA lsum, zero-C init, K/V dbuf, one barrier,
// XCD swizzle (512 blocks: id = (bh&7) | qt<<3 | (bh>>3)<<7).
// LDS 48 KB -> 2 blocks/CU.
// ---------------------------------------------------------------
__global__ __launch_bounds__(256, 2) void attn_pv(
    const ushort* __restrict__ Qb, const ushort* __restrict__ Kb,
    const ushort* __restrict__ Vtg, ushort* __restrict__ ctx,
    float* __restrict__ il2_g)
{
    __shared__ __align__(16) ushort Ks0[64*64];
    __shared__ __align__(16) ushort Ks1[64*64];
    __shared__ __align__(16) ushort Vs0[64*64];
    __shared__ __align__(16) ushort Vs1[64*64];
    __shared__ __align__(16) ushort Ps[4][32*64];   // per-wave P, XOR-swizzled

    const int id  = blockIdx.x;
    const int qt_ = (id >> 3) & 15;
    const int bh  = (id & 7) + ((id >> 7) << 3);
    const int b   = bh >> 4;
    const int h   = bh & 15;
    const int q0  = qt_ * 128;

    const int t  = threadIdx.x;
    const int w  = t >> 6;
    const int l  = t & 63;
    const int lq = l >> 4;
    const int ln = l & 15;
    const int ln7 = ln & 7;

    // Q B-fragments: q = q0 + w*32 + qs*16 + ln (Q pre-scaled by SC2)
    bf16x8 qf[2][2];
#pragma unroll
    for (int qs = 0; qs < 2; ++qs) {
        const ushort* qrow = Qb + ((size_t)(b*S_ + q0 + w*32 + qs*16 + ln))*H_ + h*HD_ + lq*8;
        qf[qs][0] = *reinterpret_cast<const bf16x8*>(qrow);
        qf[qs][1] = *reinterpret_cast<const bf16x8*>(qrow + 32);
    }

    bf16x8 onesb;
#pragma unroll
    for (int j = 0; j < 8; ++j) onesb[j] = (short)0x3F80;

    const f32x4 ZED = f32x4{0.f, 0.f, 0.f, 0.f};

    size_t koff[2], voff[2];
    int    dsto[2];
#pragma unroll
    for (int i = 0; i < 2; ++i) {
        const int chunk = i*256 + t;
        const int row   = chunk >> 3;
        const int c8    = (chunk & 7) ^ (row & 7);
        koff[i] = (size_t)(b*S_ + row)*H_ + h*HD_ + c8*8;
        voff[i] = ((size_t)((b*NH_ + h)*HD_ + row))*S_ + c8*8;
        dsto[i] = chunk*8;
    }

    f32x4 lsacc[2] = {ZED, ZED};
    f32x4 oacc[2][4];
#pragma unroll
    for (int qs = 0; qs < 2; ++qs)
#pragma unroll
        for (int nt = 0; nt < 4; ++nt) oacc[qs][nt] = ZED;

    auto tile_body = [&](const ushort* __restrict__ ksb, const ushort* __restrict__ vsb,
                         int pre_kt, bool do_pre,
                         ushort* __restrict__ kdst, ushort* __restrict__ vdst) {
        if (do_pre) {
#pragma unroll
            for (int i = 0; i < 2; ++i) {
                gload_lds16(Kb + koff[i] + (size_t)pre_kt*H_, &kdst[dsto[i]]);
                gload_lds16(Vtg + voff[i] + pre_kt, &vdst[dsto[i]]);
            }
        }

        // swapped QK^T: sacc[qs][nt], zero-C init at ks=0
        f32x4 sacc[2][4];
        {
            bf16x8 kb[4];
#pragma unroll
            for (int nt = 0; nt < 4; ++nt)
                kb[nt] = *reinterpret_cast<const bf16x8*>(
                    &ksb[(nt*16 + ln)*64 + ((lq ^ ln7) * 8)]);
#pragma unroll
            for (int qs = 0; qs < 2; ++qs)
#pragma unroll
                for (int nt = 0; nt < 4; ++nt)
                    sacc[qs][nt] = __builtin_amdgcn_mfma_f32_16x16x32_bf16(
                        kb[nt], qf[qs][0], ZED, 0, 0, 0);
        }
        {
            bf16x8 kb[4];
#pragma unroll
            for (int nt = 0; nt < 4; ++nt)
                kb[nt] = *reinterpret_cast<const bf16x8*>(
                    &ksb[(nt*16 + ln)*64 + (((4 + lq) ^ ln7) * 8)]);
#pragma unroll
            for (int qs = 0; qs < 2; ++qs)
#pragma unroll
                for (int nt = 0; nt < 4; ++nt)
                    sacc[qs][nt] = __builtin_amdgcn_mfma_f32_16x16x32_bf16(
                        kb[nt], qf[qs][1], sacc[qs][nt], 0, 0, 0);
        }

        // numerators: e = exp2(s); pack; XOR-swizzled Ps store
#pragma unroll
        for (int qs = 0; qs < 2; ++qs) {
#pragma unroll
            for (int nt = 0; nt < 4; ++nt) {
                const float e0 = exp2f(sacc[qs][nt][0]);
                const float e1 = exp2f(sacc[qs][nt][1]);
                const float e2 = exp2f(sacc[qs][nt][2]);
                const float e3 = exp2f(sacc[qs][nt][3]);
                uint2 pk;
                pk.x = cvt_pk_bf16(e0, e1);
                pk.y = cvt_pk_bf16(e2, e3);
                const int wch = (nt*2 + (lq >> 1)) ^ ln7;
                *reinterpret_cast<uint2*>(
                    &Ps[w][(qs*16 + ln)*64 + wch*8 + (lq & 1)*4]) = pk;
            }
        }

        // PV + lsum: vb read once per (ks,nt), used by both qs
#pragma unroll
        for (int ks = 0; ks < 2; ++ks) {
            bf16x8 pa[2];
#pragma unroll
            for (int qs = 0; qs < 2; ++qs) {
                pa[qs] = *reinterpret_cast<const bf16x8*>(
                    &Ps[w][(qs*16 + ln)*64 + (((ks*4 + lq) ^ ln7) * 8)]);
                lsacc[qs] = __builtin_amdgcn_mfma_f32_16x16x32_bf16(
                    pa[qs], onesb, lsacc[qs], 0, 0, 0);
            }
#pragma unroll
            for (int nt = 0; nt < 4; ++nt) {
                const bf16x8 vb8 = *reinterpret_cast<const bf16x8*>(
                    &vsb[(nt*16 + ln)*64 + (((ks*4 + lq) ^ ln7) * 8)]);
#pragma unroll
                for (int qs = 0; qs < 2; ++qs)
                    oacc[qs][nt] = __builtin_amdgcn_mfma_f32_16x16x32_bf16(
                        pa[qs], vb8, oacc[qs][nt], 0, 0, 0);
            }
        }

        __syncthreads();
    };

#pragma unroll
    for (int i = 0; i < 2; ++i) {
        gload_lds16(Kb + koff[i], &Ks0[dsto[i]]);
        gload_lds16(Vtg + voff[i], &Vs0[dsto[i]]);
    }
    __syncthreads();

    for (int kt = 0; kt < S_; kt += 128) {
        tile_body(Ks0, Vs0, kt + 64, true, Ks1, Vs1);
        tile_body(Ks1, Vs1, kt + 128, kt + 128 < S_, Ks0, Vs0);
    }

    // epilogue per qs subtile
#pragma unroll
    for (int qs = 0; qs < 2; ++qs) {
        float ivr[4];
#pragma unroll
        for (int r = 0; r < 4; ++r) ivr[r] = 1.f / lsacc[qs][r];

        if (ln == 0) {
            float4 o;
            o.x = -__log2f(lsacc[qs][0]);
            o.y = -__log2f(lsacc[qs][1]);
            o.z = -__log2f(lsacc[qs][2]);
            o.w = -__log2f(lsacc[qs][3]);
            *reinterpret_cast<float4*>(
                il2_g + (size_t)(b*NH_ + h)*S_ + q0 + w*32 + qs*16 + lq*4) = o;
        }

        ushort* crow = ctx + ((size_t)(b*S_ + q0 + w*32 + qs*16 + lq*4))*H_ + h*HD_ + ln;
#pragma unroll
        for (int r = 0; r < 4; ++r)
#pragma unroll
            for (int nt = 0; nt < 4; ++nt)
                crow[(size_t)r*H_ + nt*16] = f2bf(oacc[qs][nt][r] * ivr[r]);
    }
}

// ---------------------------------------------------------------
// fused colsum + out-projection (unchanged from round 11).
// ---------------------------------------------------------------
struct FusedArgs {
    const ushort* Qb; const ushort* Kb;
    const float*  il2; float* avg_out;
    const ushort* A;  const ushort* W;
    const float*  bias; float* Y;
};

__global__ __launch_bounds__(256) void colsum_outproj(FusedArgs fa)
{
    __shared__ __align__(16) char smem[32768];
    const int id = blockIdx.x;
    const int t  = threadIdx.x;
    const int w  = t >> 6;
    const int l  = t & 63;
    const int lq = l >> 4;
    const int ln = l & 15;
    const int ln7 = ln & 7;
    const f32x4 ZED = f32x4{0.f, 0.f, 0.f, 0.f};

    if (id < 1024) {
        // -------- colsum role (XCD-swizzled) --------
        ushort* KsT = (ushort*)smem;              // 8 KB
        ushort* Qs0 = (ushort*)(smem + 8192);     // 8 KB
        ushort* Qs1 = (ushort*)(smem + 16384);    // 8 KB
        float*  iv  = (float*)(smem + 24576);     // 8 KB

        const int kt_ = (id >> 3) & 31;
        const int bh  = (id & 7) + ((id >> 8) << 3);
        const int b   = bh >> 4;
        const int h   = bh & 15;
        const int k0  = kt_ * 64;

        int crow_[2], cc8[2], dsto[2];
#pragma unroll
        for (int i = 0; i < 2; ++i) {
            const int chunk = i*256 + t;
            crow_[i] = chunk >> 3;
            cc8[i]   = (chunk & 7) ^ (crow_[i] & 7);
            dsto[i]  = chunk*8;
        }

#pragma unroll
        for (int i = 0; i < 2; ++i) {
            gload_lds16(fa.Kb + (size_t)(b*S_ + k0 + crow_[i])*H_ + h*HD_ + cc8[i]*8, &KsT[dsto[i]]);
            gload_lds16(fa.il2 + (size_t)bh*S_ + (i*256 + t)*4, &iv[(i*256 + t)*4]);
            gload_lds16(fa.Qb + (size_t)(b*S_ + crow_[i])*H_ + h*HD_ + cc8[i]*8, &Qs0[dsto[i]]);
        }
        __syncthreads();

        bf16x8 kf[2];
#pragma unroll
        for (int ks = 0; ks < 2; ++ks)
            kf[ks] = *reinterpret_cast<const bf16x8*>(
                &KsT[(w*16 + ln)*64 + (((ks*4 + lq) ^ ln7) * 8)]);

        float cs4[4] = {0.f, 0.f, 0.f, 0.f};

        for (int qt = 0; qt < S_; qt += 128) {
#pragma unroll
            for (int i = 0; i < 2; ++i)
                gload_lds16(fa.Qb + (size_t)(b*S_ + qt + 64 + crow_[i])*H_ + h*HD_ + cc8[i]*8,
                            &Qs1[dsto[i]]);
#pragma unroll
            for (int c = 0; c < 4; ++c) {
                const bf16x8 a0 = *reinterpret_cast<const bf16x8*>(
                    &Qs0[(c*16 + ln)*64 + ((lq ^ ln7) * 8)]);
                const bf16x8 a1 = *reinterpret_cast<const bf16x8*>(
                    &Qs0[(c*16 + ln)*64 + (((4 + lq) ^ ln7) * 8)]);
                f32x4 sacc = __builtin_amdgcn_mfma_f32_16x16x32_bf16(a0, kf[0], ZED, 0, 0, 0);
                sacc = __builtin_amdgcn_mfma_f32_16x16x32_bf16(a1, kf[1], sacc, 0, 0, 0);
                const f32x4 iv4 = *reinterpret_cast<const f32x4*>(&iv[qt + c*16 + lq*4]);
#pragma unroll
                for (int r = 0; r < 4; ++r)
                    cs4[r] += exp2f(sacc[r] + iv4[r]);
            }
            __syncthreads();

            if (qt + 128 < S_) {
#pragma unroll
                for (int i = 0; i < 2; ++i)
                    gload_lds16(fa.Qb + (size_t)(b*S_ + qt + 128 + crow_[i])*H_ + h*HD_ + cc8[i]*8,
                                &Qs0[dsto[i]]);
            }
#pragma unroll
            for (int c = 0; c < 4; ++c) {
                const bf16x8 a0 = *reinterpret_cast<const bf16x8*>(
                    &Qs1[(c*16 + ln)*64 + ((lq ^ ln7) * 8)]);
                const bf16x8 a1 = *reinterpret_cast<const bf16x8*>(
                    &Qs1[(c*16 + ln)*64 + (((4 + lq) ^ ln7) * 8)]);
                f32x4 sacc = __builtin_amdgcn_mfma_f32_16x16x32_bf16(a0, kf[0], ZED, 0, 0, 0);
                sacc = __builtin_amdgcn_mfma_f32_16x16x32_bf16(a1, kf[1], sacc, 0, 0, 0);
                const f32x4 iv4 = *reinterpret_cast<const f32x4*>(&iv[qt + 64 + c*16 + lq*4]);
#pragma unroll
                for (int r = 0; r < 4; ++r)
                    cs4[r] += exp2f(sacc[r] + iv4[r]);
            }
            __syncthreads();
        }

        float cs = (cs4[0] + cs4[1]) + (cs4[2] + cs4[3]);
        cs += __shfl_xor(cs, 16);
        cs += __shfl_xor(cs, 32);
        if (l < 16)
            atomicAdd(&fa.avg_out[(size_t)b*S_ + k0 + w*16 + l], cs * AVGINV);
    } else {
        // -------- out-projection role (BM=64, BN=128, f32 out) --------
        ushort* As = (ushort*)smem;               // 8 KB
        ushort* Bs = (ushort*)(smem + 8192);      // 16 KB

        const int g  = id - 1024;
        const int m0 = (g & 63) * 64;
        const int n0 = (g >> 6) * 128;
        const int wr = w >> 1;
        const int wc = w & 1;
        const int srow = l >> 3;
        const int scol = (l & 7) * 8;

        f32x4 acc[2][4];
#pragma unroll
        for (int m = 0; m < 2; ++m)
#pragma unroll
            for (int n = 0; n < 4; ++n) acc[m][n] = ZED;

        for (int k0 = 0; k0 < H_; k0 += 64) {
            __syncthreads();
#pragma unroll
            for (int i = 0; i < 2; ++i) {
                const int rb = i*32 + w*8;
                gload_lds16(fa.A + (size_t)(m0 + rb + srow)*H_ + k0 + scol, &As[rb*64]);
            }
#pragma unroll
            for (int i = 0; i < 4; ++i) {
                const int rb = i*32 + w*8;
                gload_lds16(fa.W + (size_t)(n0 + rb + srow)*H_ + k0 + scol, &Bs[rb*64]);
            }
            __syncthreads();
#pragma unroll
            for (int ks = 0; ks < 2; ++ks) {
                bf16x8 bfr[4];
#pragma unroll
                for (int n = 0; n < 4; ++n)
                    bfr[n] = *reinterpret_cast<const bf16x8*>(&Bs[(wc*64 + n*16 + ln)*64 + ks*32 + lq*8]);
#pragma unroll
                for (int m = 0; m < 2; ++m) {
                    const bf16x8 afr = *reinterpret_cast<const bf16x8*>(&As[(wr*32 + m*16 + ln)*64 + ks*32 + lq*8]);
#pragma unroll
                    for (int n = 0; n < 4; ++n)
                        acc[m][n] = __builtin_amdgcn_mfma_f32_16x16x32_bf16(afr, bfr[n], acc[m][n], 0, 0, 0);
                }
            }
        }

        float bv[4];
#pragma unroll
        for (int n = 0; n < 4; ++n) bv[n] = fa.bias[n0 + wc*64 + n*16 + ln];

#pragma unroll
        for (int m = 0; m < 2; ++m) {
#pragma unroll
            for (int r = 0; r < 4; ++r) {
                const size_t row = (size_t)(m0 + wr*32 + m*16 + lq*4 + r);
#pragma unroll
                for (int n = 0; n < 4; ++n) {
                    const int col = n0 + wc*64 + n*16 + ln;
                    fa.Y[row*H_ + col] = acc[m][n][r] + bv[n];
                }
            }
        }
    }
}

extern "C" void kernel_launch(void* const* d_in, const int* in_sizes, int n_in,
                              void* d_out, int out_size, void* d_ws, size_t ws_size,
                              hipStream_t stream)
{
    const float* x  = (const float*)d_in[0];
    const float* Wq = (const float*)d_in[1];
    const float* bq = (const float*)d_in[2];
    const float* Wk = (const float*)d_in[3];
    const float* bk = (const float*)d_in[4];
    const float* Wv = (const float*)d_in[5];
    const float* bv = (const float*)d_in[6];
    const float* Wo = (const float*)d_in[7];
    const float* bo = (const float*)d_in[8];

    float* out     = (float*)d_out;
    float* avg_out = out + (size_t)NTOK * H_;

    char* ws = (char*)d_ws;
    const size_t mat  = (size_t)NTOK * H_ * sizeof(ushort);   // 8 MB
    const size_t wmat = (size_t)H_ * H_ * sizeof(ushort);     // 2 MB
    ushort* xb   = (ushort*)(ws);                  // also ctx (x dead after projections)
    ushort* Qb   = (ushort*)(ws + mat);
    ushort* Kb   = (ushort*)(ws + 2*mat);
    ushort* Vb   = (ushort*)(ws + 3*mat);
    ushort* Vtg  = (ushort*)(ws + 4*mat);          // V^T [(b,h)][d][s]
    ushort* Wqb  = (ushort*)(ws + 5*mat);
    ushort* Wkb  = (ushort*)(ws + 5*mat + wmat);
    ushort* Wvb  = (ushort*)(ws + 5*mat + 2*wmat);
    ushort* Wob  = (ushort*)(ws + 5*mat + 3*wmat);
    float*  il2  = (float*)(ws + 5*mat + 4*wmat);              // 256 KB
    ushort* ctxb = xb;

    const dim3 blk(256);

    // 1) all converts + avg_out zero, one launch
    {
        PrepArgs pa;
        pa.src[0] = x;  pa.dst[0] = xb;
        pa.src[1] = Wq; pa.dst[1] = Wqb;
        pa.src[2] = Wk; pa.dst[2] = Wkb;
        pa.src[3] = Wv; pa.dst[3] = Wvb;
        pa.src[4] = Wo; pa.dst[4] = Wob;
        pa.zero = avg_out;
        prep<<<dim3(4112), blk, 0, stream>>>(pa);
    }

    // 2) fused QKV projections (Q pre-scaled by SC2)
    {
        GemmArgs ga;
        ga.W[0] = Wqb; ga.W[1] = Wkb; ga.W[2] = Wvb;
        ga.bias[0] = bq; ga.bias[1] = bk; ga.bias[2] = bv;
        ga.Y[0] = Qb; ga.Y[1] = Kb; ga.Y[2] = Vb;
        ga.scale[0] = SC2; ga.scale[1] = 1.f; ga.scale[2] = 1.f;
        gemm_qkv<<<dim3(NTOK/128, H_/128, 3), blk, 0, stream>>>(xb, ga, NTOK, H_, H_);
    }

    // 3) V transpose
    transpose_v<<<dim3(S_/64, NH_, B_), blk, 0, stream>>>(Vb, Vtg);

    // 4) PV sweep, QB=128, XCD-swizzled 512-block grid
    attn_pv<<<dim3(512), blk, 0, stream>>>(Qb, Kb, Vtg, ctxb, il2);

    // 5) colsum (direct avg accumulate) || out-projection
    {
        FusedArgs fa;
        fa.Qb = Qb; fa.Kb = Kb; fa.il2 = il2; fa.avg_out = avg_out;
        fa.A = ctxb; fa.W = Wob; fa.bias = bo; fa.Y = out;
        colsum_outproj<<<dim3(1536), blk, 0, stream>>>(fa);
    }
}